// Round 2
// baseline (1476.701 us; speedup 1.0000x reference)
//
#include <hip/hip_runtime.h>
#include <hip/hip_bf16.h>

using bf16 = __hip_bfloat16;

constexpr int Bb = 32, Dd = 256, HWw = 4096, Kk = 256, Ff = 2048;
constexpr float TEMP_INV = 1.0f / 0.07f;
constexpr float EPSf = 1e-6f;
constexpr float NORM_EPSf = 1e-12f;
constexpr float LN_EPSf = 1e-5f;

static __device__ __forceinline__ float b2f(bf16 v) { return __bfloat162float(v); }
static __device__ __forceinline__ bf16 f2b(float v) { return __float2bfloat16(v); }

// ---------------- tn = l2norm(tgt, axis=d), fp32 out ----------------
__global__ __launch_bounds__(64) void k_tn(const float* __restrict__ tgt,
                                           float* __restrict__ tn) {
  int row = blockIdx.x;      // b*K + k, 8192 rows
  int lane = threadIdx.x;    // 64
  const float* src = tgt + (size_t)row * Dd + lane * 4;
  float v[4];
#pragma unroll
  for (int u = 0; u < 4; u++) v[u] = src[u];
  float ss = v[0] * v[0] + v[1] * v[1] + v[2] * v[2] + v[3] * v[3];
#pragma unroll
  for (int m = 32; m >= 1; m >>= 1) ss += __shfl_xor(ss, m, 64);
  float inv = 1.0f / fmaxf(sqrtf(ss), NORM_EPSf);
  float* dst = tn + (size_t)row * Dd + lane * 4;
#pragma unroll
  for (int u = 0; u < 4; u++) dst[u] = v[u] * inv;
}

// ---------------- nxinv[b,hw] = 1/max(||x[b,:,hw]||, eps) ----------------
__global__ __launch_bounds__(256) void k_nxinv(const float* __restrict__ x,
                                               float* __restrict__ nxinv) {
  int t = blockIdx.x * 256 + threadIdx.x;  // B*HW = 131072
  int b = t >> 12, hw = t & 4095;
  const float* px = x + (size_t)b * Dd * HWw + hw;
  float ss = 0.f;
#pragma unroll 4
  for (int d = 0; d < Dd; d++) {
    float v = px[(size_t)d * HWw];
    ss += v * v;
  }
  nxinv[t] = 1.0f / fmaxf(sqrtf(ss), NORM_EPSf);
}

// ---------------- GEMM1 + softmax over slots, write attn[b][hw][k], S sums ----------------
// block: b, 32-hw tile. BM=256 (all slots), BN=32, BK=32.
__global__ __launch_bounds__(256) void k_dots(const float* __restrict__ tn,
                                              const float* __restrict__ x,
                                              const float* __restrict__ nxinv,
                                              bf16* __restrict__ attn,
                                              float* __restrict__ S) {
  __shared__ __align__(16) float AstBuf[32 * 260];  // Ast[kk][m], pad 260
  __shared__ float Bs[32][33];
  int b = blockIdx.x >> 7;
  int hw0 = (blockIdx.x & 127) * 32;
  int tid = threadIdx.x;
  int tm = tid >> 3;   // 0..31, m = tm*8+i
  int tn_ = tid & 7;   // 0..7,  n = tn_*4+j

  float acc[8][4];
#pragma unroll
  for (int i = 0; i < 8; i++)
#pragma unroll
    for (int j = 0; j < 4; j++) acc[i][j] = 0.f;

  int dl = tid & 31;
  int kb = tid >> 5;
  for (int d0 = 0; d0 < Dd; d0 += 32) {
    // stage tn chunk transposed: Ast[dl][k]
#pragma unroll 4
    for (int p = 0; p < 32; p++) {
      int k = p * 8 + kb;
      AstBuf[dl * 260 + k] = tn[(size_t)((b << 8) + k) * Dd + d0 + dl];
    }
    // stage x chunk: Bs[dl2][c]
#pragma unroll
    for (int p = 0; p < 4; p++) {
      int dl2 = p * 8 + kb;
      Bs[dl2][dl] = x[(size_t)((b << 8) + d0 + dl2) * HWw + hw0 + dl];
    }
    __syncthreads();
#pragma unroll
    for (int kk = 0; kk < 32; kk++) {
      float a0[8], bv[4];
#pragma unroll
      for (int i = 0; i < 8; i++) a0[i] = AstBuf[kk * 260 + tm * 8 + i];
#pragma unroll
      for (int j = 0; j < 4; j++) bv[j] = Bs[kk][tn_ * 4 + j];
#pragma unroll
      for (int i = 0; i < 8; i++)
#pragma unroll
        for (int j = 0; j < 4; j++) acc[i][j] = fmaf(a0[i], bv[j], acc[i][j]);
    }
    __syncthreads();
  }

  // epilogue: alias LDS
  float* pred = AstBuf;                       // [32][33]
  float* colmax = AstBuf + 1056;              // [32]
  float* colsum = AstBuf + 1088;              // [32]
  float* sp = AstBuf + 1120;                  // [8][256]
  bf16* at = (bf16*)(AstBuf + 3168);          // [32][256]

  float inx[4];
#pragma unroll
  for (int j = 0; j < 4; j++) inx[j] = nxinv[(b << 12) + hw0 + tn_ * 4 + j];
#pragma unroll
  for (int i = 0; i < 8; i++)
#pragma unroll
    for (int j = 0; j < 4; j++) acc[i][j] *= inx[j] * TEMP_INV;

  // column max
#pragma unroll
  for (int j = 0; j < 4; j++) {
    float m = acc[0][j];
#pragma unroll
    for (int i = 1; i < 8; i++) m = fmaxf(m, acc[i][j]);
    pred[tm * 33 + tn_ * 4 + j] = m;
  }
  __syncthreads();
  if (tid < 32) {
    float m = pred[tid];
    for (int r = 1; r < 32; r++) m = fmaxf(m, pred[r * 33 + tid]);
    colmax[tid] = m;
  }
  __syncthreads();
  float cm[4];
#pragma unroll
  for (int j = 0; j < 4; j++) cm[j] = colmax[tn_ * 4 + j];
#pragma unroll
  for (int j = 0; j < 4; j++) {
    float s = 0.f;
#pragma unroll
    for (int i = 0; i < 8; i++) {
      acc[i][j] = __expf(acc[i][j] - cm[j]);
      s += acc[i][j];
    }
    pred[tm * 33 + tn_ * 4 + j] = s;
  }
  __syncthreads();
  if (tid < 32) {
    float s = 0.f;
    for (int r = 0; r < 32; r++) s += pred[r * 33 + tid];
    colsum[tid] = s;
  }
  __syncthreads();
  float ci[4];
#pragma unroll
  for (int j = 0; j < 4; j++) ci[j] = 1.0f / colsum[tn_ * 4 + j];
#pragma unroll
  for (int i = 0; i < 8; i++) {
    float rp = 0.f;
#pragma unroll
    for (int j = 0; j < 4; j++) {
      float vv = acc[i][j] * ci[j] + EPSf;
      bf16 hb = f2b(vv);
      at[(tn_ * 4 + j) * 256 + tm * 8 + i] = hb;
      rp += b2f(hb);
    }
    sp[tn_ * 256 + tm * 8 + i] = rp;
  }
  __syncthreads();
  // S partial (per slot) — sums the bf16-rounded values so the spatial
  // normalization is exactly consistent with what GEMM2 consumes.
  {
    float s = 0.f;
#pragma unroll
    for (int g = 0; g < 8; g++) s += sp[g * 256 + tid];
    atomicAdd(&S[(b << 8) + tid], s);
  }
  // coalesced attn writes
  for (int jj = 0; jj < 32; jj++)
    attn[(size_t)((b << 12) + hw0 + jj) * Kk + tid] = at[jj * 256 + tid];
}

// ---------------- GEMM2: t_pre[b,k,d] = tgt + (1/S) * sum_hw attn*x ----------------
// BM=64 (k), BN=64 (d), BK=32 (hw). grid = 32*4*4
__global__ __launch_bounds__(256) void k_gemm2(const bf16* __restrict__ attn,
                                               const float* __restrict__ x,
                                               const float* __restrict__ S,
                                               const float* __restrict__ tgt,
                                               float* __restrict__ t) {
  __shared__ __align__(16) float As2[32 * 68];
  __shared__ __align__(16) float Bs2[32 * 68];
  int b = blockIdx.x >> 4;
  int k0 = ((blockIdx.x >> 2) & 3) * 64;
  int d0 = (blockIdx.x & 3) * 64;
  int tid = threadIdx.x;
  int tng = tid & 15, tmg = tid >> 4;
  float acc[4][4];
#pragma unroll
  for (int i = 0; i < 4; i++)
#pragma unroll
    for (int j = 0; j < 4; j++) acc[i][j] = 0.f;

  for (int h0 = 0; h0 < HWw; h0 += 32) {
#pragma unroll
    for (int p = 0; p < 8; p++) {
      int id = p * 256 + tid;
      int kk = id >> 6, m = id & 63;
      As2[kk * 68 + m] = b2f(attn[(size_t)((b << 12) + h0 + kk) * Kk + k0 + m]);
    }
#pragma unroll
    for (int p = 0; p < 8; p++) {
      int id = p * 256 + tid;
      int n = id >> 5, kk = id & 31;
      Bs2[kk * 68 + n] = x[(size_t)((b << 8) + d0 + n) * HWw + h0 + kk];
    }
    __syncthreads();
#pragma unroll
    for (int kk = 0; kk < 32; kk++) {
      float a0[4], bv[4];
#pragma unroll
      for (int i = 0; i < 4; i++) a0[i] = As2[kk * 68 + tmg * 4 + i];
#pragma unroll
      for (int j = 0; j < 4; j++) bv[j] = Bs2[kk * 68 + tng * 4 + j];
#pragma unroll
      for (int i = 0; i < 4; i++)
#pragma unroll
        for (int j = 0; j < 4; j++) acc[i][j] = fmaf(a0[i], bv[j], acc[i][j]);
    }
    __syncthreads();
  }
#pragma unroll
  for (int i = 0; i < 4; i++) {
    int kq = k0 + tmg * 4 + i;
    int row = (b << 8) + kq;
    float sInv = 1.0f / S[row];
#pragma unroll
    for (int j = 0; j < 4; j++) {
      int dq = d0 + tng * 4 + j;
      t[(size_t)row * Dd + dq] = acc[i][j] * sInv + tgt[(size_t)row * Dd + dq];
    }
  }
}

// ---------------- LN1 in-place on t ----------------
__global__ __launch_bounds__(64) void k_ln1(float* __restrict__ t,
                                            const float* __restrict__ g2,
                                            const float* __restrict__ be2) {
  int row = blockIdx.x;
  int lane = threadIdx.x;
  float* p = t + (size_t)row * Dd + lane * 4;
  float v[4] = {p[0], p[1], p[2], p[3]};
  float s1 = v[0] + v[1] + v[2] + v[3];
  float s2 = v[0] * v[0] + v[1] * v[1] + v[2] * v[2] + v[3] * v[3];
#pragma unroll
  for (int m = 32; m >= 1; m >>= 1) {
    s1 += __shfl_xor(s1, m, 64);
    s2 += __shfl_xor(s2, m, 64);
  }
  float mu = s1 * (1.0f / 256.0f);
  float var = s2 * (1.0f / 256.0f) - mu * mu;
  float rs = rsqrtf(fmaxf(var, 0.f) + LN_EPSf);
#pragma unroll
  for (int u = 0; u < 4; u++)
    p[u] = (v[u] - mu) * rs * g2[lane * 4 + u] + be2[lane * 4 + u];
}

// ---------------- FFN GEMM3: h1 = relu(t @ w1^T + b1), bf16 out ----------------
// BM=64 (rows), BN=64 (f), BK=32 (d). grid = 128*32
__global__ __launch_bounds__(256) void k_ffn1(const float* __restrict__ t,
                                              const float* __restrict__ w1,
                                              const float* __restrict__ b1,
                                              bf16* __restrict__ h1) {
  __shared__ __align__(16) float As[32 * 68];
  __shared__ __align__(16) float Bs[32 * 68];
  int row0 = (blockIdx.x >> 5) * 64;
  int f0 = (blockIdx.x & 31) * 64;
  int tid = threadIdx.x;
  int tng = tid & 15, tmg = tid >> 4;
  float acc[4][4];
#pragma unroll
  for (int i = 0; i < 4; i++)
#pragma unroll
    for (int j = 0; j < 4; j++) acc[i][j] = 0.f;

  for (int d0 = 0; d0 < Dd; d0 += 32) {
#pragma unroll
    for (int p = 0; p < 8; p++) {
      int id = p * 256 + tid;
      int m = id >> 5, kk = id & 31;
      As[kk * 68 + m] = t[(size_t)(row0 + m) * Dd + d0 + kk];
      Bs[kk * 68 + m] = w1[(size_t)(f0 + m) * Dd + d0 + kk];
    }
    __syncthreads();
#pragma unroll
    for (int kk = 0; kk < 32; kk++) {
      float a0[4], bv[4];
#pragma unroll
      for (int i = 0; i < 4; i++) a0[i] = As[kk * 68 + tmg * 4 + i];
#pragma unroll
      for (int j = 0; j < 4; j++) bv[j] = Bs[kk * 68 + tng * 4 + j];
#pragma unroll
      for (int i = 0; i < 4; i++)
#pragma unroll
        for (int j = 0; j < 4; j++) acc[i][j] = fmaf(a0[i], bv[j], acc[i][j]);
    }
    __syncthreads();
  }
#pragma unroll
  for (int i = 0; i < 4; i++)
#pragma unroll
    for (int j = 0; j < 4; j++) {
      int f = f0 + tng * 4 + j;
      float v = acc[i][j] + b1[f];
      h1[(size_t)(row0 + tmg * 4 + i) * Ff + f] = f2b(fmaxf(v, 0.f));
    }
}

// ---------------- FFN GEMM4 + residual + LN2 fused → out fp32 ----------------
// BM=32 (rows), BN=256 (all d), BK=32 (f). grid = 256
__global__ __launch_bounds__(256) void k_ffn2(const bf16* __restrict__ h1,
                                              const float* __restrict__ w2,
                                              const float* __restrict__ b2v,
                                              const float* __restrict__ t,
                                              const float* __restrict__ g3,
                                              const float* __restrict__ be3,
                                              float* __restrict__ out) {
  __shared__ float As2[32 * 33];
  __shared__ __align__(16) float Bst[32 * 260];
  int row0 = blockIdx.x * 32;
  int tid = threadIdx.x;
  int tng = tid & 31, tmg = tid >> 5;
  float acc[4][8];
#pragma unroll
  for (int i = 0; i < 4; i++)
#pragma unroll
    for (int j = 0; j < 8; j++) acc[i][j] = 0.f;

  for (int f0 = 0; f0 < Ff; f0 += 32) {
#pragma unroll
    for (int p = 0; p < 4; p++) {
      int id = p * 256 + tid;
      int m = id >> 5, kk = id & 31;
      As2[kk * 33 + m] = b2f(h1[(size_t)(row0 + m) * Ff + f0 + kk]);
    }
#pragma unroll 8
    for (int p = 0; p < 32; p++) {
      int id = p * 256 + tid;
      int n = id >> 5, kk = id & 31;
      Bst[kk * 260 + n] = w2[(size_t)n * Ff + f0 + kk];
    }
    __syncthreads();
#pragma unroll
    for (int kk = 0; kk < 32; kk++) {
      float a0[4], bv[8];
#pragma unroll
      for (int i = 0; i < 4; i++) a0[i] = As2[kk * 33 + tmg * 4 + i];
#pragma unroll
      for (int j = 0; j < 8; j++) bv[j] = Bst[kk * 260 + tng * 8 + j];
#pragma unroll
      for (int i = 0; i < 4; i++)
#pragma unroll
        for (int j = 0; j < 8; j++) acc[i][j] = fmaf(a0[i], bv[j], acc[i][j]);
    }
    __syncthreads();
  }
#pragma unroll
  for (int i = 0; i < 4; i++) {
    int row = row0 + tmg * 4 + i;
    float v[8], s1 = 0.f, s2 = 0.f;
#pragma unroll
    for (int j = 0; j < 8; j++) {
      int dq = tng * 8 + j;
      float val = acc[i][j] + b2v[dq] + t[(size_t)row * Dd + dq];
      v[j] = val;
      s1 += val;
      s2 += val * val;
    }
#pragma unroll
    for (int m = 16; m >= 1; m >>= 1) {
      s1 += __shfl_xor(s1, m, 32);
      s2 += __shfl_xor(s2, m, 32);
    }
    float mu = s1 * (1.0f / 256.0f);
    float var = s2 * (1.0f / 256.0f) - mu * mu;
    float rs = rsqrtf(fmaxf(var, 0.f) + LN_EPSf);
#pragma unroll
    for (int j = 0; j < 8; j++) {
      int dq = tng * 8 + j;
      out[(size_t)row * Dd + dq] = (v[j] - mu) * rs * g3[dq] + be3[dq];
    }
  }
}

extern "C" void kernel_launch(void* const* d_in, const int* in_sizes, int n_in,
                              void* d_out, int out_size, void* d_ws, size_t ws_size,
                              hipStream_t stream) {
  // Reference dtypes are all float32 (jnp.float32 throughout setup_inputs).
  const float* x = (const float*)d_in[0];
  const float* tgt = (const float*)d_in[1];
  const float* w1 = (const float*)d_in[2];
  const float* b1 = (const float*)d_in[3];
  const float* w2 = (const float*)d_in[4];
  const float* b2v = (const float*)d_in[5];
  const float* g2 = (const float*)d_in[6];
  const float* be2 = (const float*)d_in[7];
  const float* g3 = (const float*)d_in[8];
  const float* be3 = (const float*)d_in[9];
  float* out = (float*)d_out;

  // workspace layout (~113 MB)
  char* w = (char*)d_ws;
  float* tn = (float*)w;            w += (size_t)Bb * Kk * Dd * 4;   // 8 MB
  float* nxinv = (float*)w;         w += (size_t)Bb * HWw * 4;       // 0.5 MB
  float* S = (float*)w;             w += (size_t)Bb * Kk * 4;        // 32 KB
  float* t = (float*)w;             w += (size_t)Bb * Kk * Dd * 4;   // 8 MB
  bf16* attn = (bf16*)w;            w += (size_t)Bb * HWw * Kk * 2;  // 64 MB
  bf16* h1 = (bf16*)w;              w += (size_t)Bb * Kk * Ff * 2;   // 32 MB

  hipMemsetAsync(S, 0, (size_t)Bb * Kk * 4, stream);
  k_tn<<<Bb * Kk, 64, 0, stream>>>(tgt, tn);
  k_nxinv<<<(Bb * HWw) / 256, 256, 0, stream>>>(x, nxinv);
  k_dots<<<Bb * (HWw / 32), 256, 0, stream>>>(tn, x, nxinv, attn, S);
  k_gemm2<<<Bb * 4 * 4, 256, 0, stream>>>(attn, x, S, tgt, t);
  k_ln1<<<Bb * Kk, 64, 0, stream>>>(t, g2, be2);
  k_ffn1<<<(Bb * Kk / 64) * (Ff / 64), 256, 0, stream>>>(t, w1, b1, h1);
  k_ffn2<<<Bb * Kk / 32, 256, 0, stream>>>(h1, w2, b2v, t, g3, be3, out);
}

// Round 3
// 766.585 us; speedup vs baseline: 1.9263x; 1.9263x over previous
//
#include <hip/hip_runtime.h>
#include <hip/hip_bf16.h>

using bf16 = __hip_bfloat16;

typedef __attribute__((ext_vector_type(8))) short short8;
typedef __attribute__((ext_vector_type(4))) short short4v;
typedef __attribute__((ext_vector_type(4))) float f32x4;

constexpr int Bb = 32, Dd = 256, HWw = 4096, Kk = 256, Ff = 2048;
constexpr float TEMP_INV = 1.0f / 0.07f;
constexpr float EPSf = 1e-6f;
constexpr float NORM_EPSf = 1e-12f;
constexpr float LN_EPSf = 1e-5f;

static __device__ __forceinline__ float b2f(bf16 v) { return __bfloat162float(v); }
static __device__ __forceinline__ bf16 f2b(float v) { return __float2bfloat16(v); }

// ---------------- tn = l2norm(tgt, axis=d), fp32 out ----------------
__global__ __launch_bounds__(64) void k_tn(const float* __restrict__ tgt,
                                           float* __restrict__ tn) {
  int row = blockIdx.x;
  int lane = threadIdx.x;
  const float* src = tgt + (size_t)row * Dd + lane * 4;
  float v[4];
#pragma unroll
  for (int u = 0; u < 4; u++) v[u] = src[u];
  float ss = v[0] * v[0] + v[1] * v[1] + v[2] * v[2] + v[3] * v[3];
#pragma unroll
  for (int m = 32; m >= 1; m >>= 1) ss += __shfl_xor(ss, m, 64);
  float inv = 1.0f / fmaxf(sqrtf(ss), NORM_EPSf);
  float* dst = tn + (size_t)row * Dd + lane * 4;
#pragma unroll
  for (int u = 0; u < 4; u++) dst[u] = v[u] * inv;
}

// ---------------- nxinv[b,hw] = 1/max(||x[b,:,hw]||, eps) ----------------
__global__ __launch_bounds__(256) void k_nxinv(const float* __restrict__ x,
                                               float* __restrict__ nxinv) {
  int t = blockIdx.x * 256 + threadIdx.x;
  int b = t >> 12, hw = t & 4095;
  const float* px = x + (size_t)b * Dd * HWw + hw;
  float ss = 0.f;
#pragma unroll 4
  for (int d = 0; d < Dd; d++) {
    float v = px[(size_t)d * HWw];
    ss += v * v;
  }
  nxinv[t] = 1.0f / fmaxf(sqrtf(ss), NORM_EPSf);
}

// ---------------- GEMM1 + softmax over slots -> attn_t[b][k][hw], S sums ----------------
__global__ __launch_bounds__(256) void k_dots(const float* __restrict__ tn,
                                              const float* __restrict__ x,
                                              const float* __restrict__ nxinv,
                                              bf16* __restrict__ attn_t,
                                              float* __restrict__ S) {
  __shared__ __align__(16) float AstBuf[32 * 260];
  __shared__ float Bs[32][33];
  int b = blockIdx.x >> 7;
  int hw0 = (blockIdx.x & 127) * 32;
  int tid = threadIdx.x;
  int tm = tid >> 3;   // 0..31, k = tm*8+i
  int tn_ = tid & 7;   // 0..7,  hw_l = tn_*4+j

  float acc[8][4];
#pragma unroll
  for (int i = 0; i < 8; i++)
#pragma unroll
    for (int j = 0; j < 4; j++) acc[i][j] = 0.f;

  int dl = tid & 31;
  int kb = tid >> 5;
  for (int d0 = 0; d0 < Dd; d0 += 32) {
#pragma unroll 4
    for (int p = 0; p < 32; p++) {
      int k = p * 8 + kb;
      AstBuf[dl * 260 + k] = tn[(size_t)((b << 8) + k) * Dd + d0 + dl];
    }
#pragma unroll
    for (int p = 0; p < 4; p++) {
      int dl2 = p * 8 + kb;
      Bs[dl2][dl] = x[(size_t)((b << 8) + d0 + dl2) * HWw + hw0 + dl];
    }
    __syncthreads();
#pragma unroll
    for (int kk = 0; kk < 32; kk++) {
      float a0[8], bv[4];
#pragma unroll
      for (int i = 0; i < 8; i++) a0[i] = AstBuf[kk * 260 + tm * 8 + i];
#pragma unroll
      for (int j = 0; j < 4; j++) bv[j] = Bs[kk][tn_ * 4 + j];
#pragma unroll
      for (int i = 0; i < 8; i++)
#pragma unroll
        for (int j = 0; j < 4; j++) acc[i][j] = fmaf(a0[i], bv[j], acc[i][j]);
    }
    __syncthreads();
  }

  float* pred = AstBuf;           // [32][33]
  float* colmax = AstBuf + 1056;  // [32]
  float* colsum = AstBuf + 1088;  // [32]
  float* sp = AstBuf + 1120;      // [8][256]

  float inx[4];
#pragma unroll
  for (int j = 0; j < 4; j++) inx[j] = nxinv[(b << 12) + hw0 + tn_ * 4 + j];
#pragma unroll
  for (int i = 0; i < 8; i++)
#pragma unroll
    for (int j = 0; j < 4; j++) acc[i][j] *= inx[j] * TEMP_INV;

#pragma unroll
  for (int j = 0; j < 4; j++) {
    float m = acc[0][j];
#pragma unroll
    for (int i = 1; i < 8; i++) m = fmaxf(m, acc[i][j]);
    pred[tm * 33 + tn_ * 4 + j] = m;
  }
  __syncthreads();
  if (tid < 32) {
    float m = pred[tid];
    for (int r = 1; r < 32; r++) m = fmaxf(m, pred[r * 33 + tid]);
    colmax[tid] = m;
  }
  __syncthreads();
  float cm[4];
#pragma unroll
  for (int j = 0; j < 4; j++) cm[j] = colmax[tn_ * 4 + j];
#pragma unroll
  for (int j = 0; j < 4; j++) {
    float s = 0.f;
#pragma unroll
    for (int i = 0; i < 8; i++) {
      acc[i][j] = __expf(acc[i][j] - cm[j]);
      s += acc[i][j];
    }
    pred[tm * 33 + tn_ * 4 + j] = s;
  }
  __syncthreads();
  if (tid < 32) {
    float s = 0.f;
    for (int r = 0; r < 32; r++) s += pred[r * 33 + tid];
    colsum[tid] = s;
  }
  __syncthreads();
  float ci[4];
#pragma unroll
  for (int j = 0; j < 4; j++) ci[j] = 1.0f / colsum[tn_ * 4 + j];
  // write attn_t[b][k][hw] directly: per (i), 4 consecutive hw -> 8B store, rows coalesce over tm
#pragma unroll
  for (int i = 0; i < 8; i++) {
    int k = tm * 8 + i;
    bf16 hb[4] __attribute__((aligned(8)));
    float rp = 0.f;
#pragma unroll
    for (int j = 0; j < 4; j++) {
      float vv = acc[i][j] * ci[j] + EPSf;
      hb[j] = f2b(vv);
      rp += b2f(hb[j]);
    }
    sp[tn_ * 256 + k] = rp;
    *(float2*)&attn_t[(size_t)((b << 8) + k) * HWw + hw0 + tn_ * 4] = *(float2*)hb;
  }
  __syncthreads();
  {
    float s = 0.f;
#pragma unroll
    for (int g = 0; g < 8; g++) s += sp[g * 256 + tid];
    atomicAdd(&S[(b << 8) + tid], s);
  }
}

// ---------------- MFMA tile helpers: 64x32 bf16 tile staged in fragment order ----------------
// dst[((r>>4)*64 + q*16 + (r&15))*8 + j] = src[r*ld + q*8 + j]
static __device__ __forceinline__ void stage_bf16_tile(const bf16* __restrict__ src, int ld,
                                                       bf16* __restrict__ dst, int tid) {
  int r = (tid & 15) | ((tid >> 6) << 4);
  int q = (tid >> 4) & 3;
  float4 v = *(const float4*)(src + (size_t)r * ld + q * 8);
  *(float4*)(dst + (size_t)(((r >> 4) << 6) | (q << 4) | (r & 15)) * 8) = v;
}
static __device__ __forceinline__ void stage_f32_tile(const float* __restrict__ src, int ld,
                                                      bf16* __restrict__ dst, int tid) {
  int r = (tid & 15) | ((tid >> 6) << 4);
  int q = (tid >> 4) & 3;
  const float* p = src + (size_t)r * ld + q * 8;
  float4 v0 = *(const float4*)p;
  float4 v1 = *(const float4*)(p + 4);
  bf16 tmp[8] __attribute__((aligned(16)));
  tmp[0] = f2b(v0.x); tmp[1] = f2b(v0.y); tmp[2] = f2b(v0.z); tmp[3] = f2b(v0.w);
  tmp[4] = f2b(v1.x); tmp[5] = f2b(v1.y); tmp[6] = f2b(v1.z); tmp[7] = f2b(v1.w);
  *(float4*)(dst + (size_t)(((r >> 4) << 6) | (q << 4) | (r & 15)) * 8) = *(float4*)tmp;
}

#define MFMA16(a, b, c) __builtin_amdgcn_mfma_f32_16x16x32_bf16(a, b, c, 0, 0, 0)

// ---------------- GEMM2 (MFMA): t[b,k,d] = tgt + (1/S) * attn_t . x^T ----------------
__global__ __launch_bounds__(256) void k_gemm2(const bf16* __restrict__ attn_t,
                                               const float* __restrict__ x,
                                               const float* __restrict__ S,
                                               const float* __restrict__ tgt,
                                               float* __restrict__ t) {
  __shared__ __align__(16) bf16 As[64 * 32];
  __shared__ __align__(16) bf16 Bsf[64 * 32];
  int b = blockIdx.x >> 4;
  int k0 = ((blockIdx.x >> 2) & 3) * 64;
  int d0 = (blockIdx.x & 3) * 64;
  int tid = threadIdx.x;
  int wave = tid >> 6, lane = tid & 63;
  int am = (wave >> 1) * 2, bn = (wave & 1) * 2;

  f32x4 acc[2][2];
#pragma unroll
  for (int i = 0; i < 2; i++)
#pragma unroll
    for (int j = 0; j < 2; j++) acc[i][j] = (f32x4){0.f, 0.f, 0.f, 0.f};

  const bf16* Ap = attn_t + (size_t)((b << 8) + k0) * HWw;
  const float* Bp = x + (size_t)((b << 8) + d0) * HWw;
  for (int h0 = 0; h0 < HWw; h0 += 32) {
    stage_bf16_tile(Ap + h0, HWw, As, tid);
    stage_f32_tile(Bp + h0, HWw, Bsf, tid);
    __syncthreads();
    short8 af[2], bfr[2];
#pragma unroll
    for (int i = 0; i < 2; i++) af[i] = *(const short8*)(As + (size_t)((am + i) * 64 + lane) * 8);
#pragma unroll
    for (int j = 0; j < 2; j++) bfr[j] = *(const short8*)(Bsf + (size_t)((bn + j) * 64 + lane) * 8);
#pragma unroll
    for (int i = 0; i < 2; i++)
#pragma unroll
      for (int j = 0; j < 2; j++) acc[i][j] = MFMA16(af[i], bfr[j], acc[i][j]);
    __syncthreads();
  }
  int quad = lane >> 4, nl = lane & 15;
#pragma unroll
  for (int i = 0; i < 2; i++)
#pragma unroll
    for (int r = 0; r < 4; r++) {
      int rowl = k0 + (am + i) * 16 + quad * 4 + r;
      int row = (b << 8) + rowl;
      float sInv = 1.0f / S[row];
#pragma unroll
      for (int j = 0; j < 2; j++) {
        int col = d0 + (bn + j) * 16 + nl;
        t[(size_t)row * Dd + col] = acc[i][j][r] * sInv + tgt[(size_t)row * Dd + col];
      }
    }
}

// ---------------- LN (shared by both layernorms), in-place fp32 ----------------
__global__ __launch_bounds__(64) void k_ln(float* __restrict__ t,
                                           const float* __restrict__ g,
                                           const float* __restrict__ be) {
  int row = blockIdx.x;
  int lane = threadIdx.x;
  float* p = t + (size_t)row * Dd + lane * 4;
  float v[4] = {p[0], p[1], p[2], p[3]};
  float s1 = v[0] + v[1] + v[2] + v[3];
  float s2 = v[0] * v[0] + v[1] * v[1] + v[2] * v[2] + v[3] * v[3];
#pragma unroll
  for (int m = 32; m >= 1; m >>= 1) {
    s1 += __shfl_xor(s1, m, 64);
    s2 += __shfl_xor(s2, m, 64);
  }
  float mu = s1 * (1.0f / 256.0f);
  float var = s2 * (1.0f / 256.0f) - mu * mu;
  float rs = rsqrtf(fmaxf(var, 0.f) + LN_EPSf);
#pragma unroll
  for (int u = 0; u < 4; u++)
    p[u] = (v[u] - mu) * rs * g[lane * 4 + u] + be[lane * 4 + u];
}

// ---------------- FFN GEMM3 (MFMA): h1 = relu(t @ w1^T + b1), bf16 out ----------------
__global__ __launch_bounds__(256) void k_ffn1(const float* __restrict__ t,
                                              const float* __restrict__ w1,
                                              const float* __restrict__ b1,
                                              bf16* __restrict__ h1) {
  __shared__ __align__(16) bf16 As[64 * 32];
  __shared__ __align__(16) bf16 Bsf[64 * 32];
  int row0 = (blockIdx.x >> 5) * 64;
  int f0 = (blockIdx.x & 31) * 64;
  int tid = threadIdx.x;
  int wave = tid >> 6, lane = tid & 63;
  int am = (wave >> 1) * 2, bn = (wave & 1) * 2;

  f32x4 acc[2][2];
#pragma unroll
  for (int i = 0; i < 2; i++)
#pragma unroll
    for (int j = 0; j < 2; j++) acc[i][j] = (f32x4){0.f, 0.f, 0.f, 0.f};

  const float* Ap = t + (size_t)row0 * Dd;
  const float* Bp = w1 + (size_t)f0 * Dd;
  for (int d0 = 0; d0 < Dd; d0 += 32) {
    stage_f32_tile(Ap + d0, Dd, As, tid);
    stage_f32_tile(Bp + d0, Dd, Bsf, tid);
    __syncthreads();
    short8 af[2], bfr[2];
#pragma unroll
    for (int i = 0; i < 2; i++) af[i] = *(const short8*)(As + (size_t)((am + i) * 64 + lane) * 8);
#pragma unroll
    for (int j = 0; j < 2; j++) bfr[j] = *(const short8*)(Bsf + (size_t)((bn + j) * 64 + lane) * 8);
#pragma unroll
    for (int i = 0; i < 2; i++)
#pragma unroll
      for (int j = 0; j < 2; j++) acc[i][j] = MFMA16(af[i], bfr[j], acc[i][j]);
    __syncthreads();
  }
  int quad = lane >> 4, nl = lane & 15;
#pragma unroll
  for (int j = 0; j < 2; j++) {
    int f = f0 + (bn + j) * 16 + nl;
    float bias = b1[f];
#pragma unroll
    for (int i = 0; i < 2; i++)
#pragma unroll
      for (int r = 0; r < 4; r++) {
        int row = row0 + (am + i) * 16 + quad * 4 + r;
        h1[(size_t)row * Ff + f] = f2b(fmaxf(acc[i][j][r] + bias, 0.f));
      }
  }
}

// ---------------- FFN GEMM4 (MFMA): out = h1 @ w2^T + b2 + t (pre-LN fp32) ----------------
__global__ __launch_bounds__(256) void k_ffn2(const bf16* __restrict__ h1,
                                              const float* __restrict__ w2,
                                              const float* __restrict__ b2v,
                                              const float* __restrict__ t,
                                              float* __restrict__ out) {
  __shared__ __align__(16) bf16 As[64 * 32];
  __shared__ __align__(16) bf16 Bsf[64 * 32];
  int row0 = (blockIdx.x >> 2) * 64;
  int d0 = (blockIdx.x & 3) * 64;
  int tid = threadIdx.x;
  int wave = tid >> 6, lane = tid & 63;
  int am = (wave >> 1) * 2, bn = (wave & 1) * 2;

  f32x4 acc[2][2];
#pragma unroll
  for (int i = 0; i < 2; i++)
#pragma unroll
    for (int j = 0; j < 2; j++) acc[i][j] = (f32x4){0.f, 0.f, 0.f, 0.f};

  const bf16* Ap = h1 + (size_t)row0 * Ff;
  const float* Bp = w2 + (size_t)d0 * Ff;
  for (int f0 = 0; f0 < Ff; f0 += 32) {
    stage_bf16_tile(Ap + f0, Ff, As, tid);
    stage_f32_tile(Bp + f0, Ff, Bsf, tid);
    __syncthreads();
    short8 af[2], bfr[2];
#pragma unroll
    for (int i = 0; i < 2; i++) af[i] = *(const short8*)(As + (size_t)((am + i) * 64 + lane) * 8);
#pragma unroll
    for (int j = 0; j < 2; j++) bfr[j] = *(const short8*)(Bsf + (size_t)((bn + j) * 64 + lane) * 8);
#pragma unroll
    for (int i = 0; i < 2; i++)
#pragma unroll
      for (int j = 0; j < 2; j++) acc[i][j] = MFMA16(af[i], bfr[j], acc[i][j]);
    __syncthreads();
  }
  int quad = lane >> 4, nl = lane & 15;
#pragma unroll
  for (int j = 0; j < 2; j++) {
    int col = d0 + (bn + j) * 16 + nl;
    float bias = b2v[col];
#pragma unroll
    for (int i = 0; i < 2; i++)
#pragma unroll
      for (int r = 0; r < 4; r++) {
        int row = row0 + (am + i) * 16 + quad * 4 + r;
        out[(size_t)row * Dd + col] = acc[i][j][r] + bias + t[(size_t)row * Dd + col];
      }
  }
}

extern "C" void kernel_launch(void* const* d_in, const int* in_sizes, int n_in,
                              void* d_out, int out_size, void* d_ws, size_t ws_size,
                              hipStream_t stream) {
  const float* x = (const float*)d_in[0];
  const float* tgt = (const float*)d_in[1];
  const float* w1 = (const float*)d_in[2];
  const float* b1 = (const float*)d_in[3];
  const float* w2 = (const float*)d_in[4];
  const float* b2v = (const float*)d_in[5];
  const float* g2 = (const float*)d_in[6];
  const float* be2 = (const float*)d_in[7];
  const float* g3 = (const float*)d_in[8];
  const float* be3 = (const float*)d_in[9];
  float* out = (float*)d_out;

  char* w = (char*)d_ws;
  float* tn = (float*)w;     w += (size_t)Bb * Kk * Dd * 4;   // 8 MB
  float* nxinv = (float*)w;  w += (size_t)Bb * HWw * 4;       // 0.5 MB
  float* S = (float*)w;      w += (size_t)Bb * Kk * 4;        // 32 KB
  float* t = (float*)w;      w += (size_t)Bb * Kk * Dd * 4;   // 8 MB
  bf16* attn_t = (bf16*)w;   w += (size_t)Bb * HWw * Kk * 2;  // 64 MB
  bf16* h1 = (bf16*)w;       w += (size_t)Bb * Kk * Ff * 2;   // 32 MB

  hipMemsetAsync(S, 0, (size_t)Bb * Kk * 4, stream);
  k_tn<<<Bb * Kk, 64, 0, stream>>>(tgt, tn);
  k_nxinv<<<(Bb * HWw) / 256, 256, 0, stream>>>(x, nxinv);
  k_dots<<<Bb * (HWw / 32), 256, 0, stream>>>(tn, x, nxinv, attn_t, S);
  k_gemm2<<<Bb * 16, 256, 0, stream>>>(attn_t, x, S, tgt, t);
  k_ln<<<Bb * Kk, 64, 0, stream>>>(t, g2, be2);
  k_ffn1<<<(Bb * Kk / 64) * (Ff / 64), 256, 0, stream>>>(t, w1, b1, h1);
  k_ffn2<<<(Bb * Kk / 64) * (Dd / 64), 256, 0, stream>>>(h1, w2, b2v, t, out);
  k_ln<<<Bb * Kk, 64, 0, stream>>>(out, g3, be3);
}

// Round 4
// 565.619 us; speedup vs baseline: 2.6108x; 1.3553x over previous
//
#include <hip/hip_runtime.h>
#include <hip/hip_bf16.h>

using bf16 = __hip_bfloat16;

typedef __attribute__((ext_vector_type(8))) short short8;
typedef __attribute__((ext_vector_type(4))) float f32x4;

constexpr int Bb = 32, Dd = 256, HWw = 4096, Kk = 256, Ff = 2048;
constexpr float TEMP_INV = 1.0f / 0.07f;
constexpr float EPSf = 1e-6f;
constexpr float NORM_EPSf = 1e-12f;
constexpr float LN_EPSf = 1e-5f;

static __device__ __forceinline__ float b2f(bf16 v) { return __bfloat162float(v); }
static __device__ __forceinline__ bf16 f2b(float v) { return __float2bfloat16(v); }

// ---------------- tnb = l2norm(tgt, axis=d), bf16 out ----------------
__global__ __launch_bounds__(64) void k_tn(const float* __restrict__ tgt,
                                           bf16* __restrict__ tnb) {
  int row = blockIdx.x;
  int lane = threadIdx.x;
  const float* src = tgt + (size_t)row * Dd + lane * 4;
  float v[4];
#pragma unroll
  for (int u = 0; u < 4; u++) v[u] = src[u];
  float ss = v[0] * v[0] + v[1] * v[1] + v[2] * v[2] + v[3] * v[3];
#pragma unroll
  for (int m = 32; m >= 1; m >>= 1) ss += __shfl_xor(ss, m, 64);
  float inv = 1.0f / fmaxf(sqrtf(ss), NORM_EPSf);
  bf16 o[4] __attribute__((aligned(8)));
#pragma unroll
  for (int u = 0; u < 4; u++) o[u] = f2b(v[u] * inv);
  *(float2*)(tnb + (size_t)row * Dd + lane * 4) = *(float2*)o;
}

// ---------------- nxs[b,hw] = TEMP_INV / max(||x[b,:,hw]||, eps) ----------------
__global__ __launch_bounds__(256) void k_nxinv(const float* __restrict__ x,
                                               float* __restrict__ nxs) {
  int t = blockIdx.x * 256 + threadIdx.x;
  int b = t >> 12, hw = t & 4095;
  const float* px = x + (size_t)b * Dd * HWw + hw;
  float ss = 0.f;
#pragma unroll 4
  for (int d = 0; d < Dd; d++) {
    float v = px[(size_t)d * HWw];
    ss += v * v;
  }
  nxs[t] = TEMP_INV / fmaxf(sqrtf(ss), NORM_EPSf);
}

#define MFMA16(a, b, c) __builtin_amdgcn_mfma_f32_16x16x32_bf16(a, b, c, 0, 0, 0)

// ---------------- k_dots (MFMA): logits -> softmax over slots -> attn_t[b][k][hw], S ----------------
// Block: 1 b, 64 hw columns, all 256 slots. 4 waves; wave w owns slots [w*64, w*64+64).
__global__ __launch_bounds__(256) void k_dots(const bf16* __restrict__ tnb,
                                              const float* __restrict__ x,
                                              const float* __restrict__ nxs,
                                              bf16* __restrict__ attn_t,
                                              float* __restrict__ S) {
  __shared__ __align__(16) bf16 As[16 * 64 * 8];  // A fragments: 16 KB
  __shared__ __align__(16) bf16 Bs[4 * 520];      // B fragments, per-nt pad +8: 4.06 KB
  int b = blockIdx.x >> 6;
  int hw0 = (blockIdx.x & 63) * 64;
  int tid = threadIdx.x;
  int wave = tid >> 6, lane = tid & 63;
  int quad = lane >> 4, nl = lane & 15;

  f32x4 acc[4][4];
#pragma unroll
  for (int i = 0; i < 4; i++)
#pragma unroll
    for (int j = 0; j < 4; j++) acc[i][j] = (f32x4){0.f, 0.f, 0.f, 0.f};

  // B staging map: thread -> (d-row, 8-float chunk)
  int dr = tid >> 3;          // 0..31
  int cu = (tid & 7) * 8;     // hw chunk base
  int qb = dr >> 3, jb = dr & 7;

  for (int d0 = 0; d0 < Dd; d0 += 32) {
    // stage A: 4 fragments (16 B) per thread from tnb
#pragma unroll
    for (int p = 0; p < 4; p++) {
      int fi = p * 256 + tid;
      int gmt = fi >> 6, l = fi & 63;
      int slot = (gmt << 4) | (l & 15);
      int q2 = l >> 4;
      float4 v = *(const float4*)(tnb + (size_t)((b << 8) + slot) * Dd + d0 + q2 * 8);
      *(float4*)(As + (size_t)fi * 8) = v;
    }
    // stage B transposed: read x rows (hw-contiguous), scatter bf16 into fragment order
    {
      const float* xr = x + (size_t)((b << 8) + d0 + dr) * HWw + hw0 + cu;
      float4 v0 = *(const float4*)xr;
      float4 v1 = *(const float4*)(xr + 4);
      float vv[8] = {v0.x, v0.y, v0.z, v0.w, v1.x, v1.y, v1.z, v1.w};
#pragma unroll
      for (int jj = 0; jj < 8; jj++) {
        int hwl = cu + jj;
        int nt = hwl >> 4;
        int li = (qb << 4) | (hwl & 15);
        Bs[nt * 520 + li * 8 + jb] = f2b(vv[jj]);
      }
    }
    __syncthreads();
    short8 af[4], bfv[4];
#pragma unroll
    for (int mt = 0; mt < 4; mt++)
      af[mt] = *(const short8*)(As + (size_t)(((wave << 2) + mt) * 64 + lane) * 8);
#pragma unroll
    for (int nt = 0; nt < 4; nt++)
      bfv[nt] = *(const short8*)(Bs + nt * 520 + lane * 8);
#pragma unroll
    for (int mt = 0; mt < 4; mt++)
#pragma unroll
      for (int nt = 0; nt < 4; nt++) acc[mt][nt] = MFMA16(af[mt], bfv[nt], acc[mt][nt]);
    __syncthreads();
  }

  // ---- softmax over slots (columns), fp32 in registers ----
  float sc[4];
#pragma unroll
  for (int nt = 0; nt < 4; nt++) sc[nt] = nxs[(b << 12) + hw0 + nt * 16 + nl];
#pragma unroll
  for (int mt = 0; mt < 4; mt++)
#pragma unroll
    for (int nt = 0; nt < 4; nt++)
#pragma unroll
      for (int r = 0; r < 4; r++) acc[mt][nt][r] *= sc[nt];

  float* red = (float*)As;        // [4 waves][4 nt][16 nl]
  float* red2 = red + 256;

  float pmax[4];
#pragma unroll
  for (int nt = 0; nt < 4; nt++) {
    float m = acc[0][nt][0];
#pragma unroll
    for (int mt = 0; mt < 4; mt++)
#pragma unroll
      for (int r = 0; r < 4; r++) m = fmaxf(m, acc[mt][nt][r]);
    m = fmaxf(m, __shfl_xor(m, 16, 64));
    m = fmaxf(m, __shfl_xor(m, 32, 64));
    pmax[nt] = m;
  }
  if (lane < 16) {
#pragma unroll
    for (int nt = 0; nt < 4; nt++) red[((wave << 2) + nt) * 16 + nl] = pmax[nt];
  }
  __syncthreads();
  float cmax[4];
#pragma unroll
  for (int nt = 0; nt < 4; nt++) {
    float m = red[(0 + nt) * 16 + nl];
#pragma unroll
    for (int w2 = 1; w2 < 4; w2++) m = fmaxf(m, red[((w2 << 2) + nt) * 16 + nl]);
    cmax[nt] = m;
  }

  float psum[4];
#pragma unroll
  for (int nt = 0; nt < 4; nt++) {
    float s = 0.f;
#pragma unroll
    for (int mt = 0; mt < 4; mt++)
#pragma unroll
      for (int r = 0; r < 4; r++) {
        float e = __expf(acc[mt][nt][r] - cmax[nt]);
        acc[mt][nt][r] = e;
        s += e;
      }
    s += __shfl_xor(s, 16, 64);
    s += __shfl_xor(s, 32, 64);
    psum[nt] = s;
  }
  if (lane < 16) {
#pragma unroll
    for (int nt = 0; nt < 4; nt++) red2[((wave << 2) + nt) * 16 + nl] = psum[nt];
  }
  __syncthreads();
  float ci[4];
#pragma unroll
  for (int nt = 0; nt < 4; nt++) {
    float s = 0.f;
#pragma unroll
    for (int w2 = 0; w2 < 4; w2++) s += red2[((w2 << 2) + nt) * 16 + nl];
    ci[nt] = 1.0f / s;
  }

  // ---- write attn_t (K-major) + accumulate spatial sums S (over bf16-rounded values) ----
#pragma unroll
  for (int mt = 0; mt < 4; mt++) {
    int slotg = (b << 8) + (wave << 6) + (mt << 4) + (quad << 2);
#pragma unroll
    for (int r = 0; r < 4; r++) {
      size_t base = (size_t)(slotg + r) * HWw + hw0;
      float rs = 0.f;
#pragma unroll
      for (int nt = 0; nt < 4; nt++) {
        float a = acc[mt][nt][r] * ci[nt] + EPSf;
        bf16 hb = f2b(a);
        attn_t[base + nt * 16 + nl] = hb;
        rs += b2f(hb);
      }
      rs += __shfl_xor(rs, 1, 64);
      rs += __shfl_xor(rs, 2, 64);
      rs += __shfl_xor(rs, 4, 64);
      rs += __shfl_xor(rs, 8, 64);
      if (nl == 0) atomicAdd(&S[slotg + r], rs);
    }
  }
}

// ---------------- MFMA tile helpers: 64x32 bf16 tile staged in fragment order ----------------
static __device__ __forceinline__ void stage_bf16_tile(const bf16* __restrict__ src, int ld,
                                                       bf16* __restrict__ dst, int tid) {
  int r = (tid & 15) | ((tid >> 6) << 4);
  int q = (tid >> 4) & 3;
  float4 v = *(const float4*)(src + (size_t)r * ld + q * 8);
  *(float4*)(dst + (size_t)(((r >> 4) << 6) | (q << 4) | (r & 15)) * 8) = v;
}
static __device__ __forceinline__ void stage_f32_tile(const float* __restrict__ src, int ld,
                                                      bf16* __restrict__ dst, int tid) {
  int r = (tid & 15) | ((tid >> 6) << 4);
  int q = (tid >> 4) & 3;
  const float* p = src + (size_t)r * ld + q * 8;
  float4 v0 = *(const float4*)p;
  float4 v1 = *(const float4*)(p + 4);
  bf16 tmp[8] __attribute__((aligned(16)));
  tmp[0] = f2b(v0.x); tmp[1] = f2b(v0.y); tmp[2] = f2b(v0.z); tmp[3] = f2b(v0.w);
  tmp[4] = f2b(v1.x); tmp[5] = f2b(v1.y); tmp[6] = f2b(v1.z); tmp[7] = f2b(v1.w);
  *(float4*)(dst + (size_t)(((r >> 4) << 6) | (q << 4) | (r & 15)) * 8) = *(float4*)tmp;
}

// ---------------- GEMM2 (MFMA): t[b,k,d] = tgt + (1/S) * attn_t . x^T ----------------
__global__ __launch_bounds__(256) void k_gemm2(const bf16* __restrict__ attn_t,
                                               const float* __restrict__ x,
                                               const float* __restrict__ S,
                                               const float* __restrict__ tgt,
                                               float* __restrict__ t) {
  __shared__ __align__(16) bf16 As[64 * 32];
  __shared__ __align__(16) bf16 Bsf[64 * 32];
  int b = blockIdx.x >> 4;
  int k0 = ((blockIdx.x >> 2) & 3) * 64;
  int d0 = (blockIdx.x & 3) * 64;
  int tid = threadIdx.x;
  int wave = tid >> 6, lane = tid & 63;
  int am = (wave >> 1) * 2, bn = (wave & 1) * 2;

  f32x4 acc[2][2];
#pragma unroll
  for (int i = 0; i < 2; i++)
#pragma unroll
    for (int j = 0; j < 2; j++) acc[i][j] = (f32x4){0.f, 0.f, 0.f, 0.f};

  const bf16* Ap = attn_t + (size_t)((b << 8) + k0) * HWw;
  const float* Bp = x + (size_t)((b << 8) + d0) * HWw;
  for (int h0 = 0; h0 < HWw; h0 += 32) {
    stage_bf16_tile(Ap + h0, HWw, As, tid);
    stage_f32_tile(Bp + h0, HWw, Bsf, tid);
    __syncthreads();
    short8 af[2], bfr[2];
#pragma unroll
    for (int i = 0; i < 2; i++) af[i] = *(const short8*)(As + (size_t)((am + i) * 64 + lane) * 8);
#pragma unroll
    for (int j = 0; j < 2; j++) bfr[j] = *(const short8*)(Bsf + (size_t)((bn + j) * 64 + lane) * 8);
#pragma unroll
    for (int i = 0; i < 2; i++)
#pragma unroll
      for (int j = 0; j < 2; j++) acc[i][j] = MFMA16(af[i], bfr[j], acc[i][j]);
    __syncthreads();
  }
  int quad = lane >> 4, nl = lane & 15;
#pragma unroll
  for (int i = 0; i < 2; i++)
#pragma unroll
    for (int r = 0; r < 4; r++) {
      int rowl = k0 + (am + i) * 16 + quad * 4 + r;
      int row = (b << 8) + rowl;
      float sInv = 1.0f / S[row];
#pragma unroll
      for (int j = 0; j < 2; j++) {
        int col = d0 + (bn + j) * 16 + nl;
        t[(size_t)row * Dd + col] = acc[i][j][r] * sInv + tgt[(size_t)row * Dd + col];
      }
    }
}

// ---------------- LN (shared), in-place fp32 ----------------
__global__ __launch_bounds__(64) void k_ln(float* __restrict__ t,
                                           const float* __restrict__ g,
                                           const float* __restrict__ be) {
  int row = blockIdx.x;
  int lane = threadIdx.x;
  float* p = t + (size_t)row * Dd + lane * 4;
  float v[4] = {p[0], p[1], p[2], p[3]};
  float s1 = v[0] + v[1] + v[2] + v[3];
  float s2 = v[0] * v[0] + v[1] * v[1] + v[2] * v[2] + v[3] * v[3];
#pragma unroll
  for (int m = 32; m >= 1; m >>= 1) {
    s1 += __shfl_xor(s1, m, 64);
    s2 += __shfl_xor(s2, m, 64);
  }
  float mu = s1 * (1.0f / 256.0f);
  float var = s2 * (1.0f / 256.0f) - mu * mu;
  float rs = rsqrtf(fmaxf(var, 0.f) + LN_EPSf);
#pragma unroll
  for (int u = 0; u < 4; u++)
    p[u] = (v[u] - mu) * rs * g[lane * 4 + u] + be[lane * 4 + u];
}

// ---------------- FFN GEMM3 (MFMA): h1 = relu(t @ w1^T + b1), bf16 out ----------------
__global__ __launch_bounds__(256) void k_ffn1(const float* __restrict__ t,
                                              const float* __restrict__ w1,
                                              const float* __restrict__ b1,
                                              bf16* __restrict__ h1) {
  __shared__ __align__(16) bf16 As[64 * 32];
  __shared__ __align__(16) bf16 Bsf[64 * 32];
  int row0 = (blockIdx.x >> 5) * 64;
  int f0 = (blockIdx.x & 31) * 64;
  int tid = threadIdx.x;
  int wave = tid >> 6, lane = tid & 63;
  int am = (wave >> 1) * 2, bn = (wave & 1) * 2;

  f32x4 acc[2][2];
#pragma unroll
  for (int i = 0; i < 2; i++)
#pragma unroll
    for (int j = 0; j < 2; j++) acc[i][j] = (f32x4){0.f, 0.f, 0.f, 0.f};

  const float* Ap = t + (size_t)row0 * Dd;
  const float* Bp = w1 + (size_t)f0 * Dd;
  for (int d0 = 0; d0 < Dd; d0 += 32) {
    stage_f32_tile(Ap + d0, Dd, As, tid);
    stage_f32_tile(Bp + d0, Dd, Bsf, tid);
    __syncthreads();
    short8 af[2], bfr[2];
#pragma unroll
    for (int i = 0; i < 2; i++) af[i] = *(const short8*)(As + (size_t)((am + i) * 64 + lane) * 8);
#pragma unroll
    for (int j = 0; j < 2; j++) bfr[j] = *(const short8*)(Bsf + (size_t)((bn + j) * 64 + lane) * 8);
#pragma unroll
    for (int i = 0; i < 2; i++)
#pragma unroll
      for (int j = 0; j < 2; j++) acc[i][j] = MFMA16(af[i], bfr[j], acc[i][j]);
    __syncthreads();
  }
  int quad = lane >> 4, nl = lane & 15;
#pragma unroll
  for (int j = 0; j < 2; j++) {
    int f = f0 + (bn + j) * 16 + nl;
    float bias = b1[f];
#pragma unroll
    for (int i = 0; i < 2; i++)
#pragma unroll
      for (int r = 0; r < 4; r++) {
        int row = row0 + (am + i) * 16 + quad * 4 + r;
        h1[(size_t)row * Ff + f] = f2b(fmaxf(acc[i][j][r] + bias, 0.f));
      }
  }
}

// ---------------- FFN GEMM4 (MFMA): out = h1 @ w2^T + b2 + t (pre-LN fp32) ----------------
__global__ __launch_bounds__(256) void k_ffn2(const bf16* __restrict__ h1,
                                              const float* __restrict__ w2,
                                              const float* __restrict__ b2v,
                                              const float* __restrict__ t,
                                              float* __restrict__ out) {
  __shared__ __align__(16) bf16 As[64 * 32];
  __shared__ __align__(16) bf16 Bsf[64 * 32];
  int row0 = (blockIdx.x >> 2) * 64;
  int d0 = (blockIdx.x & 3) * 64;
  int tid = threadIdx.x;
  int wave = tid >> 6, lane = tid & 63;
  int am = (wave >> 1) * 2, bn = (wave & 1) * 2;

  f32x4 acc[2][2];
#pragma unroll
  for (int i = 0; i < 2; i++)
#pragma unroll
    for (int j = 0; j < 2; j++) acc[i][j] = (f32x4){0.f, 0.f, 0.f, 0.f};

  const bf16* Ap = h1 + (size_t)row0 * Ff;
  const float* Bp = w2 + (size_t)d0 * Ff;
  for (int f0 = 0; f0 < Ff; f0 += 32) {
    stage_bf16_tile(Ap + f0, Ff, As, tid);
    stage_f32_tile(Bp + f0, Ff, Bsf, tid);
    __syncthreads();
    short8 af[2], bfr[2];
#pragma unroll
    for (int i = 0; i < 2; i++) af[i] = *(const short8*)(As + (size_t)((am + i) * 64 + lane) * 8);
#pragma unroll
    for (int j = 0; j < 2; j++) bfr[j] = *(const short8*)(Bsf + (size_t)((bn + j) * 64 + lane) * 8);
#pragma unroll
    for (int i = 0; i < 2; i++)
#pragma unroll
      for (int j = 0; j < 2; j++) acc[i][j] = MFMA16(af[i], bfr[j], acc[i][j]);
    __syncthreads();
  }
  int quad = lane >> 4, nl = lane & 15;
#pragma unroll
  for (int j = 0; j < 2; j++) {
    int col = d0 + (bn + j) * 16 + nl;
    float bias = b2v[col];
#pragma unroll
    for (int i = 0; i < 2; i++)
#pragma unroll
      for (int r = 0; r < 4; r++) {
        int row = row0 + (am + i) * 16 + quad * 4 + r;
        out[(size_t)row * Dd + col] = acc[i][j][r] + bias + t[(size_t)row * Dd + col];
      }
  }
}

extern "C" void kernel_launch(void* const* d_in, const int* in_sizes, int n_in,
                              void* d_out, int out_size, void* d_ws, size_t ws_size,
                              hipStream_t stream) {
  const float* x = (const float*)d_in[0];
  const float* tgt = (const float*)d_in[1];
  const float* w1 = (const float*)d_in[2];
  const float* b1 = (const float*)d_in[3];
  const float* w2 = (const float*)d_in[4];
  const float* b2v = (const float*)d_in[5];
  const float* g2 = (const float*)d_in[6];
  const float* be2 = (const float*)d_in[7];
  const float* g3 = (const float*)d_in[8];
  const float* be3 = (const float*)d_in[9];
  float* out = (float*)d_out;

  char* w = (char*)d_ws;
  bf16* tnb = (bf16*)w;      w += (size_t)Bb * Kk * Dd * 2;   // 4 MB
  float* nxs = (float*)w;    w += (size_t)Bb * HWw * 4;       // 0.5 MB
  float* S = (float*)w;      w += (size_t)Bb * Kk * 4;        // 32 KB
  float* t = (float*)w;      w += (size_t)Bb * Kk * Dd * 4;   // 8 MB
  bf16* attn_t = (bf16*)w;   w += (size_t)Bb * HWw * Kk * 2;  // 64 MB
  bf16* h1 = (bf16*)w;       w += (size_t)Bb * Kk * Ff * 2;   // 32 MB

  hipMemsetAsync(S, 0, (size_t)Bb * Kk * 4, stream);
  k_tn<<<Bb * Kk, 64, 0, stream>>>(tgt, tnb);
  k_nxinv<<<(Bb * HWw) / 256, 256, 0, stream>>>(x, nxs);
  k_dots<<<Bb * (HWw / 64), 256, 0, stream>>>(tnb, x, nxs, attn_t, S);
  k_gemm2<<<Bb * 16, 256, 0, stream>>>(attn_t, x, S, tgt, t);
  k_ln<<<Bb * Kk, 64, 0, stream>>>(t, g2, be2);
  k_ffn1<<<(Bb * Kk / 64) * (Ff / 64), 256, 0, stream>>>(t, w1, b1, h1);
  k_ffn2<<<(Bb * Kk / 64) * (Dd / 64), 256, 0, stream>>>(h1, w2, b2v, t, out);
  k_ln<<<Bb * Kk, 64, 0, stream>>>(out, g3, be3);
}

// Round 5
// 524.967 us; speedup vs baseline: 2.8129x; 1.0774x over previous
//
#include <hip/hip_runtime.h>
#include <hip/hip_bf16.h>

using bf16 = __hip_bfloat16;

typedef __attribute__((ext_vector_type(8))) short short8;
typedef __attribute__((ext_vector_type(4))) float f32x4;

constexpr int Bb = 32, Dd = 256, HWw = 4096, Kk = 256, Ff = 2048;
constexpr float TEMP_INV = 1.0f / 0.07f;
constexpr float EPSf = 1e-6f;
constexpr float NORM_EPSf = 1e-12f;
constexpr float LN_EPSf = 1e-5f;

static __device__ __forceinline__ float b2f(bf16 v) { return __bfloat162float(v); }
static __device__ __forceinline__ bf16 f2b(float v) { return __float2bfloat16(v); }

// ---------------- tnb = l2norm(tgt, axis=d), bf16 out ----------------
__global__ __launch_bounds__(64) void k_tn(const float* __restrict__ tgt,
                                           bf16* __restrict__ tnb) {
  int row = blockIdx.x;
  int lane = threadIdx.x;
  const float* src = tgt + (size_t)row * Dd + lane * 4;
  float v[4];
#pragma unroll
  for (int u = 0; u < 4; u++) v[u] = src[u];
  float ss = v[0] * v[0] + v[1] * v[1] + v[2] * v[2] + v[3] * v[3];
#pragma unroll
  for (int m = 32; m >= 1; m >>= 1) ss += __shfl_xor(ss, m, 64);
  float inv = 1.0f / fmaxf(sqrtf(ss), NORM_EPSf);
  bf16 o[4] __attribute__((aligned(8)));
#pragma unroll
  for (int u = 0; u < 4; u++) o[u] = f2b(v[u] * inv);
  *(float2*)(tnb + (size_t)row * Dd + lane * 4) = *(float2*)o;
}

// ---------------- nxs[b,hw] = TEMP_INV/max(||x||,eps); also xb = bf16(x) ----------------
__global__ __launch_bounds__(256) void k_nxinv(const float* __restrict__ x,
                                               float* __restrict__ nxs,
                                               bf16* __restrict__ xb) {
  int t = blockIdx.x * 256 + threadIdx.x;
  int b = t >> 12, hw = t & 4095;
  const float* px = x + (size_t)b * Dd * HWw + hw;
  bf16* pb = xb + (size_t)b * Dd * HWw + hw;
  float ss = 0.f;
#pragma unroll 4
  for (int d = 0; d < Dd; d++) {
    float v = px[(size_t)d * HWw];
    ss += v * v;
    pb[(size_t)d * HWw] = f2b(v);
  }
  nxs[t] = TEMP_INV / fmaxf(sqrtf(ss), NORM_EPSf);
}

#define MFMA16(a, b, c) __builtin_amdgcn_mfma_f32_16x16x32_bf16(a, b, c, 0, 0, 0)

// ---------------- k_dots (MFMA): logits -> softmax over slots -> attn_t[b][k][hw], S ----------------
__global__ __launch_bounds__(256) void k_dots(const bf16* __restrict__ tnb,
                                              const bf16* __restrict__ xb,
                                              const float* __restrict__ nxs,
                                              bf16* __restrict__ attn_t,
                                              float* __restrict__ S) {
  __shared__ __align__(16) bf16 As[16 * 64 * 8];  // A fragments: 16 KB
  __shared__ __align__(16) bf16 Bs[4 * 520];      // B fragments, per-nt pad +8
  int b = blockIdx.x >> 6;
  int hw0 = (blockIdx.x & 63) * 64;
  int tid = threadIdx.x;
  int wave = tid >> 6, lane = tid & 63;
  int quad = lane >> 4, nl = lane & 15;

  f32x4 acc[4][4];
#pragma unroll
  for (int i = 0; i < 4; i++)
#pragma unroll
    for (int j = 0; j < 4; j++) acc[i][j] = (f32x4){0.f, 0.f, 0.f, 0.f};

  int dr = tid >> 3;          // 0..31
  int cu = (tid & 7) * 8;     // hw chunk base
  int qb = dr >> 3, jb = dr & 7;

  for (int d0 = 0; d0 < Dd; d0 += 32) {
#pragma unroll
    for (int p = 0; p < 4; p++) {
      int fi = p * 256 + tid;
      int gmt = fi >> 6, l = fi & 63;
      int slot = (gmt << 4) | (l & 15);
      int q2 = l >> 4;
      float4 v = *(const float4*)(tnb + (size_t)((b << 8) + slot) * Dd + d0 + q2 * 8);
      *(float4*)(As + (size_t)fi * 8) = v;
    }
    {
      const bf16* xr = xb + (size_t)((b << 8) + d0 + dr) * HWw + hw0 + cu;
      short8 v = *(const short8*)xr;
#pragma unroll
      for (int jj = 0; jj < 8; jj++) {
        int hwl = cu + jj;
        int nt = hwl >> 4;
        int li = (qb << 4) | (hwl & 15);
        Bs[nt * 520 + li * 8 + jb] = ((const bf16*)&v)[jj];
      }
    }
    __syncthreads();
    short8 af[4], bfv[4];
#pragma unroll
    for (int mt = 0; mt < 4; mt++)
      af[mt] = *(const short8*)(As + (size_t)(((wave << 2) + mt) * 64 + lane) * 8);
#pragma unroll
    for (int nt = 0; nt < 4; nt++)
      bfv[nt] = *(const short8*)(Bs + nt * 520 + lane * 8);
#pragma unroll
    for (int mt = 0; mt < 4; mt++)
#pragma unroll
      for (int nt = 0; nt < 4; nt++) acc[mt][nt] = MFMA16(af[mt], bfv[nt], acc[mt][nt]);
    __syncthreads();
  }

  float sc[4];
#pragma unroll
  for (int nt = 0; nt < 4; nt++) sc[nt] = nxs[(b << 12) + hw0 + nt * 16 + nl];
#pragma unroll
  for (int mt = 0; mt < 4; mt++)
#pragma unroll
    for (int nt = 0; nt < 4; nt++)
#pragma unroll
      for (int r = 0; r < 4; r++) acc[mt][nt][r] *= sc[nt];

  float* red = (float*)As;
  float* red2 = red + 256;

  float pmax[4];
#pragma unroll
  for (int nt = 0; nt < 4; nt++) {
    float m = acc[0][nt][0];
#pragma unroll
    for (int mt = 0; mt < 4; mt++)
#pragma unroll
      for (int r = 0; r < 4; r++) m = fmaxf(m, acc[mt][nt][r]);
    m = fmaxf(m, __shfl_xor(m, 16, 64));
    m = fmaxf(m, __shfl_xor(m, 32, 64));
    pmax[nt] = m;
  }
  if (lane < 16) {
#pragma unroll
    for (int nt = 0; nt < 4; nt++) red[((wave << 2) + nt) * 16 + nl] = pmax[nt];
  }
  __syncthreads();
  float cmax[4];
#pragma unroll
  for (int nt = 0; nt < 4; nt++) {
    float m = red[nt * 16 + nl];
#pragma unroll
    for (int w2 = 1; w2 < 4; w2++) m = fmaxf(m, red[((w2 << 2) + nt) * 16 + nl]);
    cmax[nt] = m;
  }

  float psum[4];
#pragma unroll
  for (int nt = 0; nt < 4; nt++) {
    float s = 0.f;
#pragma unroll
    for (int mt = 0; mt < 4; mt++)
#pragma unroll
      for (int r = 0; r < 4; r++) {
        float e = __expf(acc[mt][nt][r] - cmax[nt]);
        acc[mt][nt][r] = e;
        s += e;
      }
    s += __shfl_xor(s, 16, 64);
    s += __shfl_xor(s, 32, 64);
    psum[nt] = s;
  }
  if (lane < 16) {
#pragma unroll
    for (int nt = 0; nt < 4; nt++) red2[((wave << 2) + nt) * 16 + nl] = psum[nt];
  }
  __syncthreads();
  float ci[4];
#pragma unroll
  for (int nt = 0; nt < 4; nt++) {
    float s = 0.f;
#pragma unroll
    for (int w2 = 0; w2 < 4; w2++) s += red2[((w2 << 2) + nt) * 16 + nl];
    ci[nt] = 1.0f / s;
  }

#pragma unroll
  for (int mt = 0; mt < 4; mt++) {
    int slotg = (b << 8) + (wave << 6) + (mt << 4) + (quad << 2);
#pragma unroll
    for (int r = 0; r < 4; r++) {
      size_t base = (size_t)(slotg + r) * HWw + hw0;
      float rs = 0.f;
#pragma unroll
      for (int nt = 0; nt < 4; nt++) {
        float a = acc[mt][nt][r] * ci[nt] + EPSf;
        bf16 hb = f2b(a);
        attn_t[base + nt * 16 + nl] = hb;
        rs += b2f(hb);
      }
      rs += __shfl_xor(rs, 1, 64);
      rs += __shfl_xor(rs, 2, 64);
      rs += __shfl_xor(rs, 4, 64);
      rs += __shfl_xor(rs, 8, 64);
      if (nl == 0) atomicAdd(&S[slotg + r], rs);
    }
  }
}

// ---------------- MFMA tile helpers ----------------
static __device__ __forceinline__ void stage_bf16_tile(const bf16* __restrict__ src, int ld,
                                                       bf16* __restrict__ dst, int tid) {
  int r = (tid & 15) | ((tid >> 6) << 4);
  int q = (tid >> 4) & 3;
  float4 v = *(const float4*)(src + (size_t)r * ld + q * 8);
  *(float4*)(dst + (size_t)(((r >> 4) << 6) | (q << 4) | (r & 15)) * 8) = v;
}
static __device__ __forceinline__ void stage_f32_tile(const float* __restrict__ src, int ld,
                                                      bf16* __restrict__ dst, int tid) {
  int r = (tid & 15) | ((tid >> 6) << 4);
  int q = (tid >> 4) & 3;
  const float* p = src + (size_t)r * ld + q * 8;
  float4 v0 = *(const float4*)p;
  float4 v1 = *(const float4*)(p + 4);
  bf16 tmp[8] __attribute__((aligned(16)));
  tmp[0] = f2b(v0.x); tmp[1] = f2b(v0.y); tmp[2] = f2b(v0.z); tmp[3] = f2b(v0.w);
  tmp[4] = f2b(v1.x); tmp[5] = f2b(v1.y); tmp[6] = f2b(v1.z); tmp[7] = f2b(v1.w);
  *(float4*)(dst + (size_t)(((r >> 4) << 6) | (q << 4) | (r & 15)) * 8) = *(float4*)tmp;
}

// ---------------- GEMM2 (MFMA, hw-split + atomic): t2[b,k,d] += attn_t . xb^T ----------------
// grid 2048: b = blockIdx & 31 (XCD-affine), tile: d fastest, then k, then hsplit.
__global__ __launch_bounds__(256) void k_gemm2(const bf16* __restrict__ attn_t,
                                               const bf16* __restrict__ xb,
                                               float* __restrict__ t2) {
  __shared__ __align__(16) bf16 As[64 * 32];
  __shared__ __align__(16) bf16 Bsf[64 * 32];
  int n = blockIdx.x;
  int b = n & 31;
  int tile = n >> 5;              // 0..63
  int d0 = (tile & 3) * 64;
  int k0 = ((tile >> 2) & 3) * 64;
  int h0b = (tile >> 4) * 1024;   // hw-chunk base
  int tid = threadIdx.x;
  int wave = tid >> 6, lane = tid & 63;
  int am = (wave >> 1) * 2, bn = (wave & 1) * 2;

  f32x4 acc[2][2];
#pragma unroll
  for (int i = 0; i < 2; i++)
#pragma unroll
    for (int j = 0; j < 2; j++) acc[i][j] = (f32x4){0.f, 0.f, 0.f, 0.f};

  const bf16* Ap = attn_t + (size_t)((b << 8) + k0) * HWw + h0b;
  const bf16* Bp = xb + (size_t)((b << 8) + d0) * HWw + h0b;
  for (int h0 = 0; h0 < 1024; h0 += 32) {
    stage_bf16_tile(Ap + h0, HWw, As, tid);
    stage_bf16_tile(Bp + h0, HWw, Bsf, tid);
    __syncthreads();
    short8 af[2], bfr[2];
#pragma unroll
    for (int i = 0; i < 2; i++) af[i] = *(const short8*)(As + (size_t)((am + i) * 64 + lane) * 8);
#pragma unroll
    for (int j = 0; j < 2; j++) bfr[j] = *(const short8*)(Bsf + (size_t)((bn + j) * 64 + lane) * 8);
#pragma unroll
    for (int i = 0; i < 2; i++)
#pragma unroll
      for (int j = 0; j < 2; j++) acc[i][j] = MFMA16(af[i], bfr[j], acc[i][j]);
    __syncthreads();
  }
  int quad = lane >> 4, nl = lane & 15;
#pragma unroll
  for (int i = 0; i < 2; i++)
#pragma unroll
    for (int r = 0; r < 4; r++) {
      int row = (b << 8) + k0 + (am + i) * 16 + quad * 4 + r;
#pragma unroll
      for (int j = 0; j < 2; j++) {
        int col = d0 + (bn + j) * 16 + nl;
        atomicAdd(&t2[(size_t)row * Dd + col], acc[i][j][r]);
      }
    }
}

// ---------------- LN_pre: t = LN(t2/S + tgt) with g2/be2 ----------------
__global__ __launch_bounds__(64) void k_ln_pre(const float* __restrict__ t2,
                                               const float* __restrict__ S,
                                               const float* __restrict__ tgt,
                                               const float* __restrict__ g,
                                               const float* __restrict__ be,
                                               float* __restrict__ t) {
  int row = blockIdx.x;
  int lane = threadIdx.x;
  float sInv = 1.0f / S[row];
  const float* p2 = t2 + (size_t)row * Dd + lane * 4;
  const float* pt = tgt + (size_t)row * Dd + lane * 4;
  float v[4];
#pragma unroll
  for (int u = 0; u < 4; u++) v[u] = p2[u] * sInv + pt[u];
  float s1 = v[0] + v[1] + v[2] + v[3];
  float s2 = v[0] * v[0] + v[1] * v[1] + v[2] * v[2] + v[3] * v[3];
#pragma unroll
  for (int m = 32; m >= 1; m >>= 1) {
    s1 += __shfl_xor(s1, m, 64);
    s2 += __shfl_xor(s2, m, 64);
  }
  float mu = s1 * (1.0f / 256.0f);
  float var = s2 * (1.0f / 256.0f) - mu * mu;
  float rs = rsqrtf(fmaxf(var, 0.f) + LN_EPSf);
  float* po = t + (size_t)row * Dd + lane * 4;
#pragma unroll
  for (int u = 0; u < 4; u++)
    po[u] = (v[u] - mu) * rs * g[lane * 4 + u] + be[lane * 4 + u];
}

// ---------------- LN (final), in-place fp32 ----------------
__global__ __launch_bounds__(64) void k_ln(float* __restrict__ t,
                                           const float* __restrict__ g,
                                           const float* __restrict__ be) {
  int row = blockIdx.x;
  int lane = threadIdx.x;
  float* p = t + (size_t)row * Dd + lane * 4;
  float v[4] = {p[0], p[1], p[2], p[3]};
  float s1 = v[0] + v[1] + v[2] + v[3];
  float s2 = v[0] * v[0] + v[1] * v[1] + v[2] * v[2] + v[3] * v[3];
#pragma unroll
  for (int m = 32; m >= 1; m >>= 1) {
    s1 += __shfl_xor(s1, m, 64);
    s2 += __shfl_xor(s2, m, 64);
  }
  float mu = s1 * (1.0f / 256.0f);
  float var = s2 * (1.0f / 256.0f) - mu * mu;
  float rs = rsqrtf(fmaxf(var, 0.f) + LN_EPSf);
#pragma unroll
  for (int u = 0; u < 4; u++)
    p[u] = (v[u] - mu) * rs * g[lane * 4 + u] + be[lane * 4 + u];
}

// ---------------- FFN GEMM3 (MFMA): h1 = relu(t @ w1^T + b1), bf16 out ----------------
__global__ __launch_bounds__(256) void k_ffn1(const float* __restrict__ t,
                                              const float* __restrict__ w1,
                                              const float* __restrict__ b1,
                                              bf16* __restrict__ h1) {
  __shared__ __align__(16) bf16 As[64 * 32];
  __shared__ __align__(16) bf16 Bsf[64 * 32];
  int row0 = (blockIdx.x >> 5) * 64;
  int f0 = (blockIdx.x & 31) * 64;
  int tid = threadIdx.x;
  int wave = tid >> 6, lane = tid & 63;
  int am = (wave >> 1) * 2, bn = (wave & 1) * 2;

  f32x4 acc[2][2];
#pragma unroll
  for (int i = 0; i < 2; i++)
#pragma unroll
    for (int j = 0; j < 2; j++) acc[i][j] = (f32x4){0.f, 0.f, 0.f, 0.f};

  const float* Ap = t + (size_t)row0 * Dd;
  const float* Bp = w1 + (size_t)f0 * Dd;
  for (int d0 = 0; d0 < Dd; d0 += 32) {
    stage_f32_tile(Ap + d0, Dd, As, tid);
    stage_f32_tile(Bp + d0, Dd, Bsf, tid);
    __syncthreads();
    short8 af[2], bfr[2];
#pragma unroll
    for (int i = 0; i < 2; i++) af[i] = *(const short8*)(As + (size_t)((am + i) * 64 + lane) * 8);
#pragma unroll
    for (int j = 0; j < 2; j++) bfr[j] = *(const short8*)(Bsf + (size_t)((bn + j) * 64 + lane) * 8);
#pragma unroll
    for (int i = 0; i < 2; i++)
#pragma unroll
      for (int j = 0; j < 2; j++) acc[i][j] = MFMA16(af[i], bfr[j], acc[i][j]);
    __syncthreads();
  }
  int quad = lane >> 4, nl = lane & 15;
#pragma unroll
  for (int j = 0; j < 2; j++) {
    int f = f0 + (bn + j) * 16 + nl;
    float bias = b1[f];
#pragma unroll
    for (int i = 0; i < 2; i++)
#pragma unroll
      for (int r = 0; r < 4; r++) {
        int row = row0 + (am + i) * 16 + quad * 4 + r;
        h1[(size_t)row * Ff + f] = f2b(fmaxf(acc[i][j][r] + bias, 0.f));
      }
  }
}

// ---------------- FFN GEMM4 (MFMA): out = h1 @ w2^T + b2 + t (pre-LN fp32) ----------------
__global__ __launch_bounds__(256) void k_ffn2(const bf16* __restrict__ h1,
                                              const float* __restrict__ w2,
                                              const float* __restrict__ b2v,
                                              const float* __restrict__ t,
                                              float* __restrict__ out) {
  __shared__ __align__(16) bf16 As[64 * 32];
  __shared__ __align__(16) bf16 Bsf[64 * 32];
  int row0 = (blockIdx.x >> 2) * 64;
  int d0 = (blockIdx.x & 3) * 64;
  int tid = threadIdx.x;
  int wave = tid >> 6, lane = tid & 63;
  int am = (wave >> 1) * 2, bn = (wave & 1) * 2;

  f32x4 acc[2][2];
#pragma unroll
  for (int i = 0; i < 2; i++)
#pragma unroll
    for (int j = 0; j < 2; j++) acc[i][j] = (f32x4){0.f, 0.f, 0.f, 0.f};

  const bf16* Ap = h1 + (size_t)row0 * Ff;
  const float* Bp = w2 + (size_t)d0 * Ff;
  for (int f0 = 0; f0 < Ff; f0 += 32) {
    stage_bf16_tile(Ap + f0, Ff, As, tid);
    stage_f32_tile(Bp + f0, Ff, Bsf, tid);
    __syncthreads();
    short8 af[2], bfr[2];
#pragma unroll
    for (int i = 0; i < 2; i++) af[i] = *(const short8*)(As + (size_t)((am + i) * 64 + lane) * 8);
#pragma unroll
    for (int j = 0; j < 2; j++) bfr[j] = *(const short8*)(Bsf + (size_t)((bn + j) * 64 + lane) * 8);
#pragma unroll
    for (int i = 0; i < 2; i++)
#pragma unroll
      for (int j = 0; j < 2; j++) acc[i][j] = MFMA16(af[i], bfr[j], acc[i][j]);
    __syncthreads();
  }
  int quad = lane >> 4, nl = lane & 15;
#pragma unroll
  for (int j = 0; j < 2; j++) {
    int col = d0 + (bn + j) * 16 + nl;
    float bias = b2v[col];
#pragma unroll
    for (int i = 0; i < 2; i++)
#pragma unroll
      for (int r = 0; r < 4; r++) {
        int row = row0 + (am + i) * 16 + quad * 4 + r;
        out[(size_t)row * Dd + col] = acc[i][j][r] + bias + t[(size_t)row * Dd + col];
      }
  }
}

extern "C" void kernel_launch(void* const* d_in, const int* in_sizes, int n_in,
                              void* d_out, int out_size, void* d_ws, size_t ws_size,
                              hipStream_t stream) {
  const float* x = (const float*)d_in[0];
  const float* tgt = (const float*)d_in[1];
  const float* w1 = (const float*)d_in[2];
  const float* b1 = (const float*)d_in[3];
  const float* w2 = (const float*)d_in[4];
  const float* b2v = (const float*)d_in[5];
  const float* g2 = (const float*)d_in[6];
  const float* be2 = (const float*)d_in[7];
  const float* g3 = (const float*)d_in[8];
  const float* be3 = (const float*)d_in[9];
  float* out = (float*)d_out;

  char* w = (char*)d_ws;
  bf16* tnb = (bf16*)w;      w += (size_t)Bb * Kk * Dd * 2;   // 4 MB
  float* nxs = (float*)w;    w += (size_t)Bb * HWw * 4;       // 0.5 MB
  float* S = (float*)w;      w += (size_t)Bb * Kk * 4;        // 32 KB
  float* t = (float*)w;      w += (size_t)Bb * Kk * Dd * 4;   // 8 MB
  float* t2 = (float*)w;     w += (size_t)Bb * Kk * Dd * 4;   // 8 MB
  bf16* attn_t = (bf16*)w;   w += (size_t)Bb * HWw * Kk * 2;  // 64 MB
  bf16* h1 = (bf16*)w;       w += (size_t)Bb * Kk * Ff * 2;   // 32 MB
  bf16* xb = (bf16*)w;       w += (size_t)Bb * Dd * HWw * 2;  // 64 MB

  hipMemsetAsync(S, 0, (size_t)Bb * Kk * 4, stream);
  hipMemsetAsync(t2, 0, (size_t)Bb * Kk * Dd * 4, stream);
  k_tn<<<Bb * Kk, 64, 0, stream>>>(tgt, tnb);
  k_nxinv<<<(Bb * HWw) / 256, 256, 0, stream>>>(x, nxs, xb);
  k_dots<<<Bb * (HWw / 64), 256, 0, stream>>>(tnb, xb, nxs, attn_t, S);
  k_gemm2<<<Bb * 64, 256, 0, stream>>>(attn_t, xb, t2);
  k_ln_pre<<<Bb * Kk, 64, 0, stream>>>(t2, S, tgt, g2, be2, t);
  k_ffn1<<<(Bb * Kk / 64) * (Ff / 64), 256, 0, stream>>>(t, w1, b1, h1);
  k_ffn2<<<(Bb * Kk / 64) * (Dd / 64), 256, 0, stream>>>(h1, w2, b2v, t, out);
  k_ln<<<Bb * Kk, 64, 0, stream>>>(out, g3, be3);
}

// Round 6
// 502.913 us; speedup vs baseline: 2.9363x; 1.0439x over previous
//
#include <hip/hip_runtime.h>
#include <hip/hip_bf16.h>

using bf16 = __hip_bfloat16;

typedef __attribute__((ext_vector_type(8))) short short8;
typedef __attribute__((ext_vector_type(4))) float f32x4;

constexpr int Bb = 32, Dd = 256, HWw = 4096, Kk = 256, Ff = 2048;
constexpr float TEMP_INV = 1.0f / 0.07f;
constexpr float EPSf = 1e-6f;
constexpr float NORM_EPSf = 1e-12f;
constexpr float LN_EPSf = 1e-5f;

static __device__ __forceinline__ float b2f(bf16 v) { return __bfloat162float(v); }
static __device__ __forceinline__ bf16 f2b(float v) { return __float2bfloat16(v); }

// ---------------- tnbf = l2norm(tgt, axis=d), bf16, MFMA A-fragment order ----------------
// Layout: per (b, s=d0/32): 1024 fragments of 8 bf16. fragment fi = (slot>>4)*64 + q2*16 + (slot&15),
// element j: d = s*32 + q2*8 + j.
__global__ __launch_bounds__(64) void k_tn(const float* __restrict__ tgt,
                                           bf16* __restrict__ tnbf) {
  int row = blockIdx.x;            // b*256 + slot
  int b = row >> 8, slot = row & 255;
  int lane = threadIdx.x;
  const float* src = tgt + (size_t)row * Dd + lane * 4;
  float v[4];
#pragma unroll
  for (int u = 0; u < 4; u++) v[u] = src[u];
  float ss = v[0] * v[0] + v[1] * v[1] + v[2] * v[2] + v[3] * v[3];
#pragma unroll
  for (int m = 32; m >= 1; m >>= 1) ss += __shfl_xor(ss, m, 64);
  float inv = 1.0f / fmaxf(sqrtf(ss), NORM_EPSf);
  bf16 o[4] __attribute__((aligned(8)));
#pragma unroll
  for (int u = 0; u < 4; u++) o[u] = f2b(v[u] * inv);
  int s = lane >> 3;
  int q2 = (lane >> 1) & 3;
  int jh = (lane & 1) * 4;
  size_t fi = (size_t)((slot >> 4) * 64 + q2 * 16 + (slot & 15));
  *(float2*)(tnbf + ((size_t)(b * 8 + s) * 1024 + fi) * 8 + jh) = *(float2*)o;
}

#define MFMA16(a, b, c) __builtin_amdgcn_mfma_f32_16x16x32_bf16(a, b, c, 0, 0, 0)

// ---------------- k_dots (MFMA, fused x-norm): logits -> softmax(slots) -> attn_t, xb, S ----------------
// Block: 1 b, 64 hw columns, all 256 slots. Also computes nxs inline and emits xb = bf16(x).
__global__ __launch_bounds__(256) void k_dots(const bf16* __restrict__ tnbf,
                                              const float* __restrict__ x,
                                              bf16* __restrict__ xb,
                                              bf16* __restrict__ attn_t,
                                              float* __restrict__ S) {
  __shared__ __align__(16) bf16 As[16 * 64 * 8];  // A fragments: 16 KB
  __shared__ __align__(16) bf16 Bs[4 * 520];      // B fragments, per-nt pad +8
  __shared__ float ssred[64 * 17];                // x^2 partials [hw][dp], pad 17
  __shared__ float nxl[64];
  int b = blockIdx.x >> 6;
  int hw0 = (blockIdx.x & 63) * 64;
  int tid = threadIdx.x;
  int wave = tid >> 6, lane = tid & 63;
  int quad = lane >> 4, nl = lane & 15;

  // B staging map: thread -> (d-pair dp, 4-hw chunk ch)
  int dp = tid >> 4;           // 0..15
  int ch = tid & 15;           // 0..15
  int qb = dp >> 2;            // (2dp)>>3
  int jb = (dp & 3) * 2;       // (2dp)&7

  f32x4 acc[4][4];
#pragma unroll
  for (int i = 0; i < 4; i++)
#pragma unroll
    for (int j = 0; j < 4; j++) acc[i][j] = (f32x4){0.f, 0.f, 0.f, 0.f};
  float ssp[4] = {0.f, 0.f, 0.f, 0.f};

  for (int s = 0; s < 8; s++) {
    // stage A: fully-coalesced copy of pre-fragmented tn
    const bf16* tsrc = tnbf + (size_t)(b * 8 + s) * 1024 * 8;
#pragma unroll
    for (int p = 0; p < 4; p++) {
      int fi = p * 256 + tid;
      *(float4*)(As + (size_t)fi * 8) = *(const float4*)(tsrc + (size_t)fi * 8);
    }
    // stage B: read x fp32 (2 d-rows x 4 hw), accumulate x^2, emit xb bf16, scatter packed b32
    {
      const float* xr = x + (size_t)((b << 8) + s * 32 + 2 * dp) * HWw + hw0 + ch * 4;
      float4 va = *(const float4*)xr;
      float4 vb = *(const float4*)(xr + HWw);
      float vva[4] = {va.x, va.y, va.z, va.w};
      float vvb[4] = {vb.x, vb.y, vb.z, vb.w};
      bf16 pa[4] __attribute__((aligned(8)));
      bf16 pb[4] __attribute__((aligned(8)));
#pragma unroll
      for (int jj = 0; jj < 4; jj++) {
        ssp[jj] += vva[jj] * vva[jj] + vvb[jj] * vvb[jj];
        pa[jj] = f2b(vva[jj]);
        pb[jj] = f2b(vvb[jj]);
      }
      bf16* xw = xb + (size_t)((b << 8) + s * 32 + 2 * dp) * HWw + hw0 + ch * 4;
      *(float2*)xw = *(float2*)pa;
      *(float2*)(xw + HWw) = *(float2*)pb;
#pragma unroll
      for (int jj = 0; jj < 4; jj++) {
        int hwl = ch * 4 + jj;
        int nt = hwl >> 4;
        int li = (qb << 4) | (hwl & 15);
        union { bf16 h[2]; unsigned int u; } pk;
        pk.h[0] = pa[jj];
        pk.h[1] = pb[jj];
        *(unsigned int*)&Bs[nt * 520 + li * 8 + jb] = pk.u;
      }
    }
    __syncthreads();
    short8 af[4], bfv[4];
#pragma unroll
    for (int mt = 0; mt < 4; mt++)
      af[mt] = *(const short8*)(As + (size_t)(((wave << 2) + mt) * 64 + lane) * 8);
#pragma unroll
    for (int nt = 0; nt < 4; nt++)
      bfv[nt] = *(const short8*)(Bs + nt * 520 + lane * 8);
#pragma unroll
    for (int mt = 0; mt < 4; mt++)
#pragma unroll
      for (int nt = 0; nt < 4; nt++) acc[mt][nt] = MFMA16(af[mt], bfv[nt], acc[mt][nt]);
    __syncthreads();
  }

  // ---- finish column norms: reduce ssp over dp ----
#pragma unroll
  for (int jj = 0; jj < 4; jj++) ssred[(ch * 4 + jj) * 17 + dp] = ssp[jj];
  __syncthreads();
  if (tid < 64) {
    float sum = 0.f;
#pragma unroll
    for (int i = 0; i < 16; i++) sum += ssred[tid * 17 + i];
    nxl[tid] = TEMP_INV / fmaxf(sqrtf(sum), NORM_EPSf);
  }
  __syncthreads();

  float sc[4];
#pragma unroll
  for (int nt = 0; nt < 4; nt++) sc[nt] = nxl[nt * 16 + nl];
#pragma unroll
  for (int mt = 0; mt < 4; mt++)
#pragma unroll
    for (int nt = 0; nt < 4; nt++)
#pragma unroll
      for (int r = 0; r < 4; r++) acc[mt][nt][r] *= sc[nt];

  float* red = (float*)As;
  float* red2 = red + 256;

  float pmax[4];
#pragma unroll
  for (int nt = 0; nt < 4; nt++) {
    float m = acc[0][nt][0];
#pragma unroll
    for (int mt = 0; mt < 4; mt++)
#pragma unroll
      for (int r = 0; r < 4; r++) m = fmaxf(m, acc[mt][nt][r]);
    m = fmaxf(m, __shfl_xor(m, 16, 64));
    m = fmaxf(m, __shfl_xor(m, 32, 64));
    pmax[nt] = m;
  }
  if (lane < 16) {
#pragma unroll
    for (int nt = 0; nt < 4; nt++) red[((wave << 2) + nt) * 16 + nl] = pmax[nt];
  }
  __syncthreads();
  float cmax[4];
#pragma unroll
  for (int nt = 0; nt < 4; nt++) {
    float m = red[nt * 16 + nl];
#pragma unroll
    for (int w2 = 1; w2 < 4; w2++) m = fmaxf(m, red[((w2 << 2) + nt) * 16 + nl]);
    cmax[nt] = m;
  }

  float psum[4];
#pragma unroll
  for (int nt = 0; nt < 4; nt++) {
    float s = 0.f;
#pragma unroll
    for (int mt = 0; mt < 4; mt++)
#pragma unroll
      for (int r = 0; r < 4; r++) {
        float e = __expf(acc[mt][nt][r] - cmax[nt]);
        acc[mt][nt][r] = e;
        s += e;
      }
    s += __shfl_xor(s, 16, 64);
    s += __shfl_xor(s, 32, 64);
    psum[nt] = s;
  }
  if (lane < 16) {
#pragma unroll
    for (int nt = 0; nt < 4; nt++) red2[((wave << 2) + nt) * 16 + nl] = psum[nt];
  }
  __syncthreads();
  float ci[4];
#pragma unroll
  for (int nt = 0; nt < 4; nt++) {
    float s = 0.f;
#pragma unroll
    for (int w2 = 0; w2 < 4; w2++) s += red2[((w2 << 2) + nt) * 16 + nl];
    ci[nt] = 1.0f / s;
  }

#pragma unroll
  for (int mt = 0; mt < 4; mt++) {
    int slotg = (b << 8) + (wave << 6) + (mt << 4) + (quad << 2);
#pragma unroll
    for (int r = 0; r < 4; r++) {
      size_t base = (size_t)(slotg + r) * HWw + hw0;
      float rs = 0.f;
#pragma unroll
      for (int nt = 0; nt < 4; nt++) {
        float a = acc[mt][nt][r] * ci[nt] + EPSf;
        bf16 hb = f2b(a);
        attn_t[base + nt * 16 + nl] = hb;
        rs += b2f(hb);
      }
      rs += __shfl_xor(rs, 1, 64);
      rs += __shfl_xor(rs, 2, 64);
      rs += __shfl_xor(rs, 4, 64);
      rs += __shfl_xor(rs, 8, 64);
      if (nl == 0) atomicAdd(&S[slotg + r], rs);
    }
  }
}

// ---------------- MFMA tile helpers ----------------
static __device__ __forceinline__ void stage_bf16_tile(const bf16* __restrict__ src, int ld,
                                                       bf16* __restrict__ dst, int tid) {
  int r = (tid & 15) | ((tid >> 6) << 4);
  int q = (tid >> 4) & 3;
  float4 v = *(const float4*)(src + (size_t)r * ld + q * 8);
  *(float4*)(dst + (size_t)(((r >> 4) << 6) | (q << 4) | (r & 15)) * 8) = v;
}
static __device__ __forceinline__ void stage_f32_tile(const float* __restrict__ src, int ld,
                                                      bf16* __restrict__ dst, int tid) {
  int r = (tid & 15) | ((tid >> 6) << 4);
  int q = (tid >> 4) & 3;
  const float* p = src + (size_t)r * ld + q * 8;
  float4 v0 = *(const float4*)p;
  float4 v1 = *(const float4*)(p + 4);
  bf16 tmp[8] __attribute__((aligned(16)));
  tmp[0] = f2b(v0.x); tmp[1] = f2b(v0.y); tmp[2] = f2b(v0.z); tmp[3] = f2b(v0.w);
  tmp[4] = f2b(v1.x); tmp[5] = f2b(v1.y); tmp[6] = f2b(v1.z); tmp[7] = f2b(v1.w);
  *(float4*)(dst + (size_t)(((r >> 4) << 6) | (q << 4) | (r & 15)) * 8) = *(float4*)tmp;
}

// ---------------- GEMM2 (MFMA, hw-split + atomic): t2[b,k,d] += attn_t . xb^T ----------------
__global__ __launch_bounds__(256) void k_gemm2(const bf16* __restrict__ attn_t,
                                               const bf16* __restrict__ xb,
                                               float* __restrict__ t2) {
  __shared__ __align__(16) bf16 As[64 * 32];
  __shared__ __align__(16) bf16 Bsf[64 * 32];
  int n = blockIdx.x;
  int b = n & 31;
  int tile = n >> 5;              // 0..63
  int d0 = (tile & 3) * 64;
  int k0 = ((tile >> 2) & 3) * 64;
  int h0b = (tile >> 4) * 1024;
  int tid = threadIdx.x;
  int wave = tid >> 6, lane = tid & 63;
  int am = (wave >> 1) * 2, bn = (wave & 1) * 2;

  f32x4 acc[2][2];
#pragma unroll
  for (int i = 0; i < 2; i++)
#pragma unroll
    for (int j = 0; j < 2; j++) acc[i][j] = (f32x4){0.f, 0.f, 0.f, 0.f};

  const bf16* Ap = attn_t + (size_t)((b << 8) + k0) * HWw + h0b;
  const bf16* Bp = xb + (size_t)((b << 8) + d0) * HWw + h0b;
  for (int h0 = 0; h0 < 1024; h0 += 32) {
    stage_bf16_tile(Ap + h0, HWw, As, tid);
    stage_bf16_tile(Bp + h0, HWw, Bsf, tid);
    __syncthreads();
    short8 af[2], bfr[2];
#pragma unroll
    for (int i = 0; i < 2; i++) af[i] = *(const short8*)(As + (size_t)((am + i) * 64 + lane) * 8);
#pragma unroll
    for (int j = 0; j < 2; j++) bfr[j] = *(const short8*)(Bsf + (size_t)((bn + j) * 64 + lane) * 8);
#pragma unroll
    for (int i = 0; i < 2; i++)
#pragma unroll
      for (int j = 0; j < 2; j++) acc[i][j] = MFMA16(af[i], bfr[j], acc[i][j]);
    __syncthreads();
  }
  int quad = lane >> 4, nl = lane & 15;
#pragma unroll
  for (int i = 0; i < 2; i++)
#pragma unroll
    for (int r = 0; r < 4; r++) {
      int row = (b << 8) + k0 + (am + i) * 16 + quad * 4 + r;
#pragma unroll
      for (int j = 0; j < 2; j++) {
        int col = d0 + (bn + j) * 16 + nl;
        atomicAdd(&t2[(size_t)row * Dd + col], acc[i][j][r]);
      }
    }
}

// ---------------- LN_pre: t = LN(t2/S + tgt) with g2/be2 ----------------
__global__ __launch_bounds__(64) void k_ln_pre(const float* __restrict__ t2,
                                               const float* __restrict__ S,
                                               const float* __restrict__ tgt,
                                               const float* __restrict__ g,
                                               const float* __restrict__ be,
                                               float* __restrict__ t) {
  int row = blockIdx.x;
  int lane = threadIdx.x;
  float sInv = 1.0f / S[row];
  const float* p2 = t2 + (size_t)row * Dd + lane * 4;
  const float* pt = tgt + (size_t)row * Dd + lane * 4;
  float v[4];
#pragma unroll
  for (int u = 0; u < 4; u++) v[u] = p2[u] * sInv + pt[u];
  float s1 = v[0] + v[1] + v[2] + v[3];
  float s2 = v[0] * v[0] + v[1] * v[1] + v[2] * v[2] + v[3] * v[3];
#pragma unroll
  for (int m = 32; m >= 1; m >>= 1) {
    s1 += __shfl_xor(s1, m, 64);
    s2 += __shfl_xor(s2, m, 64);
  }
  float mu = s1 * (1.0f / 256.0f);
  float var = s2 * (1.0f / 256.0f) - mu * mu;
  float rs = rsqrtf(fmaxf(var, 0.f) + LN_EPSf);
  float* po = t + (size_t)row * Dd + lane * 4;
#pragma unroll
  for (int u = 0; u < 4; u++)
    po[u] = (v[u] - mu) * rs * g[lane * 4 + u] + be[lane * 4 + u];
}

// ---------------- LN (final), in-place fp32 ----------------
__global__ __launch_bounds__(64) void k_ln(float* __restrict__ t,
                                           const float* __restrict__ g,
                                           const float* __restrict__ be) {
  int row = blockIdx.x;
  int lane = threadIdx.x;
  float* p = t + (size_t)row * Dd + lane * 4;
  float v[4] = {p[0], p[1], p[2], p[3]};
  float s1 = v[0] + v[1] + v[2] + v[3];
  float s2 = v[0] * v[0] + v[1] * v[1] + v[2] * v[2] + v[3] * v[3];
#pragma unroll
  for (int m = 32; m >= 1; m >>= 1) {
    s1 += __shfl_xor(s1, m, 64);
    s2 += __shfl_xor(s2, m, 64);
  }
  float mu = s1 * (1.0f / 256.0f);
  float var = s2 * (1.0f / 256.0f) - mu * mu;
  float rs = rsqrtf(fmaxf(var, 0.f) + LN_EPSf);
#pragma unroll
  for (int u = 0; u < 4; u++)
    p[u] = (v[u] - mu) * rs * g[lane * 4 + u] + be[lane * 4 + u];
}

// ---------------- FFN GEMM3 (MFMA): h1 = relu(t @ w1^T + b1), bf16 out ----------------
__global__ __launch_bounds__(256) void k_ffn1(const float* __restrict__ t,
                                              const float* __restrict__ w1,
                                              const float* __restrict__ b1,
                                              bf16* __restrict__ h1) {
  __shared__ __align__(16) bf16 As[64 * 32];
  __shared__ __align__(16) bf16 Bsf[64 * 32];
  int row0 = (blockIdx.x >> 5) * 64;
  int f0 = (blockIdx.x & 31) * 64;
  int tid = threadIdx.x;
  int wave = tid >> 6, lane = tid & 63;
  int am = (wave >> 1) * 2, bn = (wave & 1) * 2;

  f32x4 acc[2][2];
#pragma unroll
  for (int i = 0; i < 2; i++)
#pragma unroll
    for (int j = 0; j < 2; j++) acc[i][j] = (f32x4){0.f, 0.f, 0.f, 0.f};

  const float* Ap = t + (size_t)row0 * Dd;
  const float* Bp = w1 + (size_t)f0 * Dd;
  for (int d0 = 0; d0 < Dd; d0 += 32) {
    stage_f32_tile(Ap + d0, Dd, As, tid);
    stage_f32_tile(Bp + d0, Dd, Bsf, tid);
    __syncthreads();
    short8 af[2], bfr[2];
#pragma unroll
    for (int i = 0; i < 2; i++) af[i] = *(const short8*)(As + (size_t)((am + i) * 64 + lane) * 8);
#pragma unroll
    for (int j = 0; j < 2; j++) bfr[j] = *(const short8*)(Bsf + (size_t)((bn + j) * 64 + lane) * 8);
#pragma unroll
    for (int i = 0; i < 2; i++)
#pragma unroll
      for (int j = 0; j < 2; j++) acc[i][j] = MFMA16(af[i], bfr[j], acc[i][j]);
    __syncthreads();
  }
  int quad = lane >> 4, nl = lane & 15;
#pragma unroll
  for (int j = 0; j < 2; j++) {
    int f = f0 + (bn + j) * 16 + nl;
    float bias = b1[f];
#pragma unroll
    for (int i = 0; i < 2; i++)
#pragma unroll
      for (int r = 0; r < 4; r++) {
        int row = row0 + (am + i) * 16 + quad * 4 + r;
        h1[(size_t)row * Ff + f] = f2b(fmaxf(acc[i][j][r] + bias, 0.f));
      }
  }
}

// ---------------- FFN GEMM4 (MFMA): out = h1 @ w2^T + b2 + t (pre-LN fp32) ----------------
__global__ __launch_bounds__(256) void k_ffn2(const bf16* __restrict__ h1,
                                              const float* __restrict__ w2,
                                              const float* __restrict__ b2v,
                                              const float* __restrict__ t,
                                              float* __restrict__ out) {
  __shared__ __align__(16) bf16 As[64 * 32];
  __shared__ __align__(16) bf16 Bsf[64 * 32];
  int row0 = (blockIdx.x >> 2) * 64;
  int d0 = (blockIdx.x & 3) * 64;
  int tid = threadIdx.x;
  int wave = tid >> 6, lane = tid & 63;
  int am = (wave >> 1) * 2, bn = (wave & 1) * 2;

  f32x4 acc[2][2];
#pragma unroll
  for (int i = 0; i < 2; i++)
#pragma unroll
    for (int j = 0; j < 2; j++) acc[i][j] = (f32x4){0.f, 0.f, 0.f, 0.f};

  const bf16* Ap = h1 + (size_t)row0 * Ff;
  const float* Bp = w2 + (size_t)d0 * Ff;
  for (int f0 = 0; f0 < Ff; f0 += 32) {
    stage_bf16_tile(Ap + f0, Ff, As, tid);
    stage_f32_tile(Bp + f0, Ff, Bsf, tid);
    __syncthreads();
    short8 af[2], bfr[2];
#pragma unroll
    for (int i = 0; i < 2; i++) af[i] = *(const short8*)(As + (size_t)((am + i) * 64 + lane) * 8);
#pragma unroll
    for (int j = 0; j < 2; j++) bfr[j] = *(const short8*)(Bsf + (size_t)((bn + j) * 64 + lane) * 8);
#pragma unroll
    for (int i = 0; i < 2; i++)
#pragma unroll
      for (int j = 0; j < 2; j++) acc[i][j] = MFMA16(af[i], bfr[j], acc[i][j]);
    __syncthreads();
  }
  int quad = lane >> 4, nl = lane & 15;
#pragma unroll
  for (int j = 0; j < 2; j++) {
    int col = d0 + (bn + j) * 16 + nl;
    float bias = b2v[col];
#pragma unroll
    for (int i = 0; i < 2; i++)
#pragma unroll
      for (int r = 0; r < 4; r++) {
        int row = row0 + (am + i) * 16 + quad * 4 + r;
        out[(size_t)row * Dd + col] = acc[i][j][r] + bias + t[(size_t)row * Dd + col];
      }
  }
}

extern "C" void kernel_launch(void* const* d_in, const int* in_sizes, int n_in,
                              void* d_out, int out_size, void* d_ws, size_t ws_size,
                              hipStream_t stream) {
  const float* x = (const float*)d_in[0];
  const float* tgt = (const float*)d_in[1];
  const float* w1 = (const float*)d_in[2];
  const float* b1 = (const float*)d_in[3];
  const float* w2 = (const float*)d_in[4];
  const float* b2v = (const float*)d_in[5];
  const float* g2 = (const float*)d_in[6];
  const float* be2 = (const float*)d_in[7];
  const float* g3 = (const float*)d_in[8];
  const float* be3 = (const float*)d_in[9];
  float* out = (float*)d_out;

  char* w = (char*)d_ws;
  bf16* tnbf = (bf16*)w;     w += (size_t)Bb * Kk * Dd * 2;   // 4 MB (fragment order)
  float* S = (float*)w;      w += (size_t)Bb * Kk * 4;        // 32 KB
  float* t = (float*)w;      w += (size_t)Bb * Kk * Dd * 4;   // 8 MB
  float* t2 = (float*)w;     w += (size_t)Bb * Kk * Dd * 4;   // 8 MB
  bf16* attn_t = (bf16*)w;   w += (size_t)Bb * HWw * Kk * 2;  // 64 MB
  bf16* h1 = (bf16*)w;       w += (size_t)Bb * Kk * Ff * 2;   // 32 MB
  bf16* xb = (bf16*)w;       w += (size_t)Bb * Dd * HWw * 2;  // 64 MB

  hipMemsetAsync(S, 0, (size_t)Bb * Kk * 4, stream);
  hipMemsetAsync(t2, 0, (size_t)Bb * Kk * Dd * 4, stream);
  k_tn<<<Bb * Kk, 64, 0, stream>>>(tgt, tnbf);
  k_dots<<<Bb * (HWw / 64), 256, 0, stream>>>(tnbf, x, xb, attn_t, S);
  k_gemm2<<<Bb * 64, 256, 0, stream>>>(attn_t, xb, t2);
  k_ln_pre<<<Bb * Kk, 64, 0, stream>>>(t2, S, tgt, g2, be2, t);
  k_ffn1<<<(Bb * Kk / 64) * (Ff / 64), 256, 0, stream>>>(t, w1, b1, h1);
  k_ffn2<<<(Bb * Kk / 64) * (Dd / 64), 256, 0, stream>>>(h1, w2, b2v, t, out);
  k_ln<<<Bb * Kk, 64, 0, stream>>>(out, g3, be3);
}

// Round 8
// 460.427 us; speedup vs baseline: 3.2072x; 1.0923x over previous
//
#include <hip/hip_runtime.h>
#include <hip/hip_bf16.h>

using bf16 = __hip_bfloat16;

typedef __attribute__((ext_vector_type(8))) short short8;
typedef __attribute__((ext_vector_type(4))) float f32x4;

constexpr int Bb = 32, Dd = 256, HWw = 4096, Kk = 256, Ff = 2048;
constexpr float TEMP_INV = 1.0f / 0.07f;
constexpr float EPSf = 1e-6f;
constexpr float NORM_EPSf = 1e-12f;
constexpr float LN_EPSf = 1e-5f;

static __device__ __forceinline__ float b2f(bf16 v) { return __bfloat162float(v); }
static __device__ __forceinline__ bf16 f2b(float v) { return __float2bfloat16(v); }

// Fragment layouts:
//  - 256-row group (tnbf): per (grp,s): 1024 frags; fi = (row>>4)*64 + q2*16 + (row&15)
//  - 64-row group (tbf/w1bf/w2bf): per (grp,s): 256 frags; fi = ((row&63)>>4)*64 + q2*16 + (row&15)
// Fragment elem j: k = s*32 + q2*8 + j. Reader lane: quad=lane>>4 ↔ q2, nl=lane&15 ↔ row&15.

// ---------------- k_tn: tnbf = l2norm(tgt) bf16, 256-row-group fragment order ----------------
__global__ __launch_bounds__(64) void k_tn(const float* __restrict__ tgt,
                                           bf16* __restrict__ tnbf) {
  int row = blockIdx.x;            // b*256 + slot
  int b = row >> 8, slot = row & 255;
  int lane = threadIdx.x;
  const float* src = tgt + (size_t)row * Dd + lane * 4;
  float v[4];
#pragma unroll
  for (int u = 0; u < 4; u++) v[u] = src[u];
  float ss = v[0] * v[0] + v[1] * v[1] + v[2] * v[2] + v[3] * v[3];
#pragma unroll
  for (int m = 32; m >= 1; m >>= 1) ss += __shfl_xor(ss, m, 64);
  float inv = 1.0f / fmaxf(sqrtf(ss), NORM_EPSf);
  bf16 o[4] __attribute__((aligned(8)));
#pragma unroll
  for (int u = 0; u < 4; u++) o[u] = f2b(v[u] * inv);
  int s = lane >> 3;
  int q2 = (lane >> 1) & 3;
  int jh = (lane & 1) * 4;
  size_t fi = (size_t)((slot >> 4) * 64 + q2 * 16 + (slot & 15));
  *(float2*)(tnbf + ((size_t)(b * 8 + s) * 1024 + fi) * 8 + jh) = *(float2*)o;
}

// ---------------- k_prew1: w1 (DFFxD fp32) -> 64-row-group fragment order bf16 ----------------
__global__ __launch_bounds__(64) void k_prew1(const float* __restrict__ w1,
                                              bf16* __restrict__ w1bf) {
  int f = blockIdx.x;              // 0..2047
  int lane = threadIdx.x;
  const float* src = w1 + (size_t)f * Dd + lane * 4;
  bf16 o[4] __attribute__((aligned(8)));
#pragma unroll
  for (int u = 0; u < 4; u++) o[u] = f2b(src[u]);
  int s = lane >> 3;
  int q2 = (lane >> 1) & 3;
  int jh = (lane & 1) * 4;
  size_t fi = (size_t)(((f & 63) >> 4) * 64 + q2 * 16 + (f & 15));
  *(float2*)(w1bf + ((size_t)((f >> 6) * 8 + s) * 256 + fi) * 8 + jh) = *(float2*)o;
}

// ---------------- k_prew2: w2 (DxDFF fp32) -> 64-row-group fragment order (64 f-steps) ----------------
__global__ __launch_bounds__(64) void k_prew2(const float* __restrict__ w2,
                                              bf16* __restrict__ w2bf) {
  int d = blockIdx.x;              // 0..255
  int lane = threadIdx.x;          // sg = lane (f-step)
  const float* src = w2 + (size_t)d * Ff + lane * 32;
  size_t gbase = (size_t)((d >> 6) * 64 + lane) * 256;
  int fbase = ((d & 63) >> 4) * 64 + (d & 15);
#pragma unroll
  for (int q2 = 0; q2 < 4; q2++) {
    float4 v0 = *(const float4*)(src + q2 * 8);
    float4 v1 = *(const float4*)(src + q2 * 8 + 4);
    bf16 o[8] __attribute__((aligned(16)));
    o[0] = f2b(v0.x); o[1] = f2b(v0.y); o[2] = f2b(v0.z); o[3] = f2b(v0.w);
    o[4] = f2b(v1.x); o[5] = f2b(v1.y); o[6] = f2b(v1.z); o[7] = f2b(v1.w);
    *(float4*)(w2bf + (gbase + fbase + q2 * 16) * 8) = *(float4*)o;
  }
}

#define MFMA16(a, b, c) __builtin_amdgcn_mfma_f32_16x16x32_bf16(a, b, c, 0, 0, 0)

// ---------------- k_dots (MFMA, fused x-norm, direct-A): softmax(slots) -> attn_t, xb, S ----------------
__global__ __launch_bounds__(256) void k_dots(const bf16* __restrict__ tnbf,
                                              const float* __restrict__ x,
                                              bf16* __restrict__ xb,
                                              bf16* __restrict__ attn_t,
                                              float* __restrict__ S) {
  __shared__ __align__(16) bf16 Bs[2][4 * 520];   // double-buffered B fragments
  __shared__ float ssred[64 * 17];
  __shared__ float nxl[64];
  __shared__ float red[512];
  int b = blockIdx.x >> 6;
  int hw0 = (blockIdx.x & 63) * 64;
  int tid = threadIdx.x;
  int wave = tid >> 6, lane = tid & 63;
  int quad = lane >> 4, nl = lane & 15;

  int dp = tid >> 4;           // 0..15
  int ch = tid & 15;           // 0..15
  int qb = dp >> 2;
  int jb = (dp & 3) * 2;

  f32x4 acc[4][4];
#pragma unroll
  for (int i = 0; i < 4; i++)
#pragma unroll
    for (int j = 0; j < 4; j++) acc[i][j] = (f32x4){0.f, 0.f, 0.f, 0.f};
  float ssp[4] = {0.f, 0.f, 0.f, 0.f};

  for (int s = 0; s < 8; s++) {
    bf16* bsb = &Bs[s & 1][0];
    {
      const float* xr = x + (size_t)((b << 8) + s * 32 + 2 * dp) * HWw + hw0 + ch * 4;
      float4 va = *(const float4*)xr;
      float4 vb = *(const float4*)(xr + HWw);
      float vva[4] = {va.x, va.y, va.z, va.w};
      float vvb[4] = {vb.x, vb.y, vb.z, vb.w};
      bf16 pa[4] __attribute__((aligned(8)));
      bf16 pb[4] __attribute__((aligned(8)));
#pragma unroll
      for (int jj = 0; jj < 4; jj++) {
        ssp[jj] += vva[jj] * vva[jj] + vvb[jj] * vvb[jj];
        pa[jj] = f2b(vva[jj]);
        pb[jj] = f2b(vvb[jj]);
      }
      bf16* xw = xb + (size_t)((b << 8) + s * 32 + 2 * dp) * HWw + hw0 + ch * 4;
      *(float2*)xw = *(float2*)pa;
      *(float2*)(xw + HWw) = *(float2*)pb;
#pragma unroll
      for (int jj = 0; jj < 4; jj++) {
        int hwl = ch * 4 + jj;
        int nt = hwl >> 4;
        int li = (qb << 4) | (hwl & 15);
        union { bf16 h[2]; unsigned int u; } pk;
        pk.h[0] = pa[jj];
        pk.h[1] = pb[jj];
        *(unsigned int*)&bsb[nt * 520 + li * 8 + jb] = pk.u;
      }
    }
    __syncthreads();
    const bf16* tsrc = tnbf + (size_t)(b * 8 + s) * 1024 * 8;
    short8 af[4], bfv[4];
#pragma unroll
    for (int mt = 0; mt < 4; mt++)
      af[mt] = *(const short8*)(tsrc + (size_t)(((wave << 2) + mt) * 64 + lane) * 8);
#pragma unroll
    for (int nt = 0; nt < 4; nt++)
      bfv[nt] = *(const short8*)(bsb + nt * 520 + lane * 8);
#pragma unroll
    for (int mt = 0; mt < 4; mt++)
#pragma unroll
      for (int nt = 0; nt < 4; nt++) acc[mt][nt] = MFMA16(af[mt], bfv[nt], acc[mt][nt]);
  }

#pragma unroll
  for (int jj = 0; jj < 4; jj++) ssred[(ch * 4 + jj) * 17 + dp] = ssp[jj];
  __syncthreads();
  if (tid < 64) {
    float sum = 0.f;
#pragma unroll
    for (int i = 0; i < 16; i++) sum += ssred[tid * 17 + i];
    nxl[tid] = TEMP_INV / fmaxf(sqrtf(sum), NORM_EPSf);
  }
  __syncthreads();

  float sc[4];
#pragma unroll
  for (int nt = 0; nt < 4; nt++) sc[nt] = nxl[nt * 16 + nl];
#pragma unroll
  for (int mt = 0; mt < 4; mt++)
#pragma unroll
    for (int nt = 0; nt < 4; nt++)
#pragma unroll
      for (int r = 0; r < 4; r++) acc[mt][nt][r] *= sc[nt];

  float* red2 = red + 256;

  float pmax[4];
#pragma unroll
  for (int nt = 0; nt < 4; nt++) {
    float m = acc[0][nt][0];
#pragma unroll
    for (int mt = 0; mt < 4; mt++)
#pragma unroll
      for (int r = 0; r < 4; r++) m = fmaxf(m, acc[mt][nt][r]);
    m = fmaxf(m, __shfl_xor(m, 16, 64));
    m = fmaxf(m, __shfl_xor(m, 32, 64));
    pmax[nt] = m;
  }
  if (lane < 16) {
#pragma unroll
    for (int nt = 0; nt < 4; nt++) red[((wave << 2) + nt) * 16 + nl] = pmax[nt];
  }
  __syncthreads();
  float cmax[4];
#pragma unroll
  for (int nt = 0; nt < 4; nt++) {
    float m = red[nt * 16 + nl];
#pragma unroll
    for (int w2 = 1; w2 < 4; w2++) m = fmaxf(m, red[((w2 << 2) + nt) * 16 + nl]);
    cmax[nt] = m;
  }

  float psum[4];
#pragma unroll
  for (int nt = 0; nt < 4; nt++) {
    float s = 0.f;
#pragma unroll
    for (int mt = 0; mt < 4; mt++)
#pragma unroll
      for (int r = 0; r < 4; r++) {
        float e = __expf(acc[mt][nt][r] - cmax[nt]);
        acc[mt][nt][r] = e;
        s += e;
      }
    s += __shfl_xor(s, 16, 64);
    s += __shfl_xor(s, 32, 64);
    psum[nt] = s;
  }
  if (lane < 16) {
#pragma unroll
    for (int nt = 0; nt < 4; nt++) red2[((wave << 2) + nt) * 16 + nl] = psum[nt];
  }
  __syncthreads();
  float ci[4];
#pragma unroll
  for (int nt = 0; nt < 4; nt++) {
    float s = 0.f;
#pragma unroll
    for (int w2 = 0; w2 < 4; w2++) s += red2[((w2 << 2) + nt) * 16 + nl];
    ci[nt] = 1.0f / s;
  }

#pragma unroll
  for (int mt = 0; mt < 4; mt++) {
    int slotg = (b << 8) + (wave << 6) + (mt << 4) + (quad << 2);
#pragma unroll
    for (int r = 0; r < 4; r++) {
      size_t base = (size_t)(slotg + r) * HWw + hw0;
      float rs = 0.f;
#pragma unroll
      for (int nt = 0; nt < 4; nt++) {
        float a = acc[mt][nt][r] * ci[nt] + EPSf;
        bf16 hb = f2b(a);
        attn_t[base + nt * 16 + nl] = hb;
        rs += b2f(hb);
      }
      rs += __shfl_xor(rs, 1, 64);
      rs += __shfl_xor(rs, 2, 64);
      rs += __shfl_xor(rs, 4, 64);
      rs += __shfl_xor(rs, 8, 64);
      if (nl == 0) atomicAdd(&S[slotg + r], rs);
    }
  }
}

// ---------------- LDS tile helper (64x32 bf16, fragment order) ----------------
static __device__ __forceinline__ void stage_bf16_tile(const bf16* __restrict__ src, int ld,
                                                       bf16* __restrict__ dst, int tid) {
  int r = (tid & 15) | ((tid >> 6) << 4);
  int q = (tid >> 4) & 3;
  float4 v = *(const float4*)(src + (size_t)r * ld + q * 8);
  *(float4*)(dst + (size_t)(((r >> 4) << 6) | (q << 4) | (r & 15)) * 8) = v;
}

// ---------------- GEMM2 (MFMA, hw-split + atomic): t2[b,k,d] += attn_t . xb^T ----------------
__global__ __launch_bounds__(256) void k_gemm2(const bf16* __restrict__ attn_t,
                                               const bf16* __restrict__ xb,
                                               float* __restrict__ t2) {
  __shared__ __align__(16) bf16 As[64 * 32];
  __shared__ __align__(16) bf16 Bsf[64 * 32];
  int n = blockIdx.x;
  int b = n & 31;
  int tile = n >> 5;
  int d0 = (tile & 3) * 64;
  int k0 = ((tile >> 2) & 3) * 64;
  int h0b = (tile >> 4) * 1024;
  int tid = threadIdx.x;
  int wave = tid >> 6, lane = tid & 63;
  int am = (wave >> 1) * 2, bn = (wave & 1) * 2;

  f32x4 acc[2][2];
#pragma unroll
  for (int i = 0; i < 2; i++)
#pragma unroll
    for (int j = 0; j < 2; j++) acc[i][j] = (f32x4){0.f, 0.f, 0.f, 0.f};

  const bf16* Ap = attn_t + (size_t)((b << 8) + k0) * HWw + h0b;
  const bf16* Bp = xb + (size_t)((b << 8) + d0) * HWw + h0b;
  for (int h0 = 0; h0 < 1024; h0 += 32) {
    stage_bf16_tile(Ap + h0, HWw, As, tid);
    stage_bf16_tile(Bp + h0, HWw, Bsf, tid);
    __syncthreads();
    short8 af[2], bfr[2];
#pragma unroll
    for (int i = 0; i < 2; i++) af[i] = *(const short8*)(As + (size_t)((am + i) * 64 + lane) * 8);
#pragma unroll
    for (int j = 0; j < 2; j++) bfr[j] = *(const short8*)(Bsf + (size_t)((bn + j) * 64 + lane) * 8);
#pragma unroll
    for (int i = 0; i < 2; i++)
#pragma unroll
      for (int j = 0; j < 2; j++) acc[i][j] = MFMA16(af[i], bfr[j], acc[i][j]);
    __syncthreads();
  }
  int quad = lane >> 4, nl = lane & 15;
#pragma unroll
  for (int i = 0; i < 2; i++)
#pragma unroll
    for (int r = 0; r < 4; r++) {
      int row = (b << 8) + k0 + (am + i) * 16 + quad * 4 + r;
#pragma unroll
      for (int j = 0; j < 2; j++) {
        int col = d0 + (bn + j) * 16 + nl;
        atomicAdd(&t2[(size_t)row * Dd + col], acc[i][j][r]);
      }
    }
}

// ---------------- LN_pre: t = LN(t2/S + tgt); also tbf (64-row-group fragment order) ----------------
__global__ __launch_bounds__(64) void k_ln_pre(const float* __restrict__ t2,
                                               const float* __restrict__ S,
                                               const float* __restrict__ tgt,
                                               const float* __restrict__ g,
                                               const float* __restrict__ be,
                                               float* __restrict__ t,
                                               bf16* __restrict__ tbf) {
  int row = blockIdx.x;
  int lane = threadIdx.x;
  float sInv = 1.0f / S[row];
  const float* p2 = t2 + (size_t)row * Dd + lane * 4;
  const float* pt = tgt + (size_t)row * Dd + lane * 4;
  float v[4];
#pragma unroll
  for (int u = 0; u < 4; u++) v[u] = p2[u] * sInv + pt[u];
  float s1 = v[0] + v[1] + v[2] + v[3];
  float s2 = v[0] * v[0] + v[1] * v[1] + v[2] * v[2] + v[3] * v[3];
#pragma unroll
  for (int m = 32; m >= 1; m >>= 1) {
    s1 += __shfl_xor(s1, m, 64);
    s2 += __shfl_xor(s2, m, 64);
  }
  float mu = s1 * (1.0f / 256.0f);
  float var = s2 * (1.0f / 256.0f) - mu * mu;
  float rs = rsqrtf(fmaxf(var, 0.f) + LN_EPSf);
  float* po = t + (size_t)row * Dd + lane * 4;
  bf16 o[4] __attribute__((aligned(8)));
#pragma unroll
  for (int u = 0; u < 4; u++) {
    float val = (v[u] - mu) * rs * g[lane * 4 + u] + be[lane * 4 + u];
    po[u] = val;
    o[u] = f2b(val);
  }
  int s = lane >> 3;
  int q2 = (lane >> 1) & 3;
  int jh = (lane & 1) * 4;
  size_t fi = (size_t)(((row & 63) >> 4) * 64 + q2 * 16 + (row & 15));
  *(float2*)(tbf + ((size_t)((row >> 6) * 8 + s) * 256 + fi) * 8 + jh) = *(float2*)o;
}

// ---------------- FFN GEMM3 (MFMA, zero-LDS): h1 = relu(tbf @ w1bf^T + b1) ----------------
__global__ __launch_bounds__(256) void k_ffn1(const bf16* __restrict__ tbf,
                                              const bf16* __restrict__ w1bf,
                                              const float* __restrict__ b1,
                                              bf16* __restrict__ h1) {
  int rowgrp = blockIdx.x >> 5;    // 0..127
  int fgrp = blockIdx.x & 31;      // 0..31
  int tid = threadIdx.x;
  int wave = tid >> 6, lane = tid & 63;
  int am = (wave >> 1) * 2, bn = (wave & 1) * 2;

  f32x4 acc[2][2];
#pragma unroll
  for (int i = 0; i < 2; i++)
#pragma unroll
    for (int j = 0; j < 2; j++) acc[i][j] = (f32x4){0.f, 0.f, 0.f, 0.f};

  const bf16* Abase = tbf + (size_t)rowgrp * 8 * 256 * 8;
  const bf16* Bbase = w1bf + (size_t)fgrp * 8 * 256 * 8;
#pragma unroll
  for (int s = 0; s < 8; s++) {
    short8 af[2], bfr[2];
#pragma unroll
    for (int i = 0; i < 2; i++)
      af[i] = *(const short8*)(Abase + ((size_t)s * 256 + ((am + i) * 64 + lane)) * 8);
#pragma unroll
    for (int j = 0; j < 2; j++)
      bfr[j] = *(const short8*)(Bbase + ((size_t)s * 256 + ((bn + j) * 64 + lane)) * 8);
#pragma unroll
    for (int i = 0; i < 2; i++)
#pragma unroll
      for (int j = 0; j < 2; j++) acc[i][j] = MFMA16(af[i], bfr[j], acc[i][j]);
  }
  int quad = lane >> 4, nl = lane & 15;
  int row0 = rowgrp * 64, f0 = fgrp * 64;
#pragma unroll
  for (int j = 0; j < 2; j++) {
    int f = f0 + (bn + j) * 16 + nl;
    float bias = b1[f];
#pragma unroll
    for (int i = 0; i < 2; i++)
#pragma unroll
      for (int r = 0; r < 4; r++) {
        int row = row0 + (am + i) * 16 + quad * 4 + r;
        h1[(size_t)row * Ff + f] = f2b(fmaxf(acc[i][j][r] + bias, 0.f));
      }
  }
}

// ---------------- FFN GEMM4 (MFMA, split-K + atomic): o2 += h1 @ w2^T ----------------
__global__ __launch_bounds__(256) void k_ffn2(const bf16* __restrict__ h1,
                                              const bf16* __restrict__ w2bf,
                                              float* __restrict__ o2) {
  __shared__ __align__(16) bf16 As[64 * 32];
  int n = blockIdx.x;
  int rowgrp = n >> 4;             // 0..127
  int dgrp = (n >> 2) & 3;         // 0..3
  int ksp = n & 3;                 // 0..3
  int tid = threadIdx.x;
  int wave = tid >> 6, lane = tid & 63;
  int am = (wave >> 1) * 2, bn = (wave & 1) * 2;

  f32x4 acc[2][2];
#pragma unroll
  for (int i = 0; i < 2; i++)
#pragma unroll
    for (int j = 0; j < 2; j++) acc[i][j] = (f32x4){0.f, 0.f, 0.f, 0.f};

  const bf16* Ap = h1 + (size_t)(rowgrp * 64) * Ff + ksp * 512;
  const bf16* Bbase = w2bf + (size_t)dgrp * 64 * 256 * 8;
  for (int st = 0; st < 16; st++) {
    int sg = ksp * 16 + st;
    stage_bf16_tile(Ap + st * 32, Ff, As, tid);
    __syncthreads();
    short8 af[2], bfr[2];
#pragma unroll
    for (int i = 0; i < 2; i++) af[i] = *(const short8*)(As + (size_t)((am + i) * 64 + lane) * 8);
#pragma unroll
    for (int j = 0; j < 2; j++)
      bfr[j] = *(const short8*)(Bbase + ((size_t)sg * 256 + ((bn + j) * 64 + lane)) * 8);
#pragma unroll
    for (int i = 0; i < 2; i++)
#pragma unroll
      for (int j = 0; j < 2; j++) acc[i][j] = MFMA16(af[i], bfr[j], acc[i][j]);
    __syncthreads();
  }
  int quad = lane >> 4, nl = lane & 15;
#pragma unroll
  for (int i = 0; i < 2; i++)
#pragma unroll
    for (int r = 0; r < 4; r++) {
      int row = rowgrp * 64 + (am + i) * 16 + quad * 4 + r;
#pragma unroll
      for (int j = 0; j < 2; j++) {
        int col = dgrp * 64 + (bn + j) * 16 + nl;
        atomicAdd(&o2[(size_t)row * Dd + col], acc[i][j][r]);
      }
    }
}

// ---------------- LN_out: out = LN(o2 + b2 + t) with g3/be3 ----------------
__global__ __launch_bounds__(64) void k_ln_out(const float* __restrict__ o2,
                                               const float* __restrict__ b2v,
                                               const float* __restrict__ t,
                                               const float* __restrict__ g,
                                               const float* __restrict__ be,
                                               float* __restrict__ out) {
  int row = blockIdx.x;
  int lane = threadIdx.x;
  const float* po = o2 + (size_t)row * Dd + lane * 4;
  const float* pt = t + (size_t)row * Dd + lane * 4;
  float v[4];
#pragma unroll
  for (int u = 0; u < 4; u++) v[u] = po[u] + b2v[lane * 4 + u] + pt[u];
  float s1 = v[0] + v[1] + v[2] + v[3];
  float s2 = v[0] * v[0] + v[1] * v[1] + v[2] * v[2] + v[3] * v[3];
#pragma unroll
  for (int m = 32; m >= 1; m >>= 1) {
    s1 += __shfl_xor(s1, m, 64);
    s2 += __shfl_xor(s2, m, 64);
  }
  float mu = s1 * (1.0f / 256.0f);
  float var = s2 * (1.0f / 256.0f) - mu * mu;
  float rs = rsqrtf(fmaxf(var, 0.f) + LN_EPSf);
  float* pw = out + (size_t)row * Dd + lane * 4;
#pragma unroll
  for (int u = 0; u < 4; u++)
    pw[u] = (v[u] - mu) * rs * g[lane * 4 + u] + be[lane * 4 + u];
}

extern "C" void kernel_launch(void* const* d_in, const int* in_sizes, int n_in,
                              void* d_out, int out_size, void* d_ws, size_t ws_size,
                              hipStream_t stream) {
  const float* x = (const float*)d_in[0];
  const float* tgt = (const float*)d_in[1];
  const float* w1 = (const float*)d_in[2];
  const float* b1 = (const float*)d_in[3];
  const float* w2 = (const float*)d_in[4];
  const float* b2v = (const float*)d_in[5];
  const float* g2 = (const float*)d_in[6];
  const float* be2 = (const float*)d_in[7];
  const float* g3 = (const float*)d_in[8];
  const float* be3 = (const float*)d_in[9];
  float* out = (float*)d_out;

  // R6-proven 180 MB footprint; new buffers alias dead regions:
  //   tbf  -> tnbf  (tnbf dead after k_dots)
  //   o2   -> t2    (t2 dead after k_ln_pre; re-zeroed mid-stream)
  //   w1bf/w2bf -> head of attn_t (attn_t dead after k_gemm2; prew kernels run after gemm2)
  char* w = (char*)d_ws;
  bf16* tnbf = (bf16*)w;     w += (size_t)Bb * Kk * Dd * 2;   // 4 MB
  float* S = (float*)w;      w += (size_t)Bb * Kk * 4;        // 32 KB
  float* t = (float*)w;      w += (size_t)Bb * Kk * Dd * 4;   // 8 MB
  float* t2 = (float*)w;     w += (size_t)Bb * Kk * Dd * 4;   // 8 MB
  bf16* attn_t = (bf16*)w;   w += (size_t)Bb * HWw * Kk * 2;  // 64 MB
  bf16* h1 = (bf16*)w;       w += (size_t)Bb * Kk * Ff * 2;   // 32 MB
  bf16* xb = (bf16*)w;       w += (size_t)Bb * Dd * HWw * 2;  // 64 MB

  bf16* tbf = tnbf;                      // 4 MB alias
  float* o2 = t2;                        // 8 MB alias
  bf16* w1bf = attn_t;                   // 1 MB carve
  bf16* w2bf = attn_t + (size_t)Ff * Dd; // 1 MB carve

  hipMemsetAsync(S, 0, (size_t)Bb * Kk * 4, stream);
  hipMemsetAsync(t2, 0, (size_t)Bb * Kk * Dd * 4, stream);
  k_tn<<<Bb * Kk, 64, 0, stream>>>(tgt, tnbf);
  k_dots<<<Bb * (HWw / 64), 256, 0, stream>>>(tnbf, x, xb, attn_t, S);
  k_gemm2<<<Bb * 64, 256, 0, stream>>>(attn_t, xb, t2);
  k_prew1<<<Ff, 64, 0, stream>>>(w1, w1bf);
  k_prew2<<<Dd, 64, 0, stream>>>(w2, w2bf);
  k_ln_pre<<<Bb * Kk, 64, 0, stream>>>(t2, S, tgt, g2, be2, t, tbf);
  hipMemsetAsync(o2, 0, (size_t)Bb * Kk * Dd * 4, stream);
  k_ffn1<<<(Bb * Kk / 64) * (Ff / 64), 256, 0, stream>>>(tbf, w1bf, b1, h1);
  k_ffn2<<<(Bb * Kk / 64) * 16, 256, 0, stream>>>(h1, w2bf, o2);
  k_ln_out<<<Bb * Kk, 64, 0, stream>>>(o2, b2v, t, g3, be3, out);
}

// Round 9
// 460.130 us; speedup vs baseline: 3.2093x; 1.0006x over previous
//
#include <hip/hip_runtime.h>
#include <hip/hip_bf16.h>

using bf16 = __hip_bfloat16;

typedef __attribute__((ext_vector_type(8))) short short8;
typedef __attribute__((ext_vector_type(4))) float f32x4;

constexpr int Bb = 32, Dd = 256, HWw = 4096, Kk = 256, Ff = 2048;
constexpr float TEMP_INV = 1.0f / 0.07f;
constexpr float EPSf = 1e-6f;
constexpr float NORM_EPSf = 1e-12f;
constexpr float LN_EPSf = 1e-5f;

static __device__ __forceinline__ float b2f(bf16 v) { return __bfloat162float(v); }
static __device__ __forceinline__ bf16 f2b(float v) { return __float2bfloat16(v); }

// Fragment layouts:
//  - 256-row group (tnbf): per (grp,s): 1024 frags; fi = (row>>4)*64 + q2*16 + (row&15)
//  - 64-row group (tbf/w1bf/w2bf): per (grp,s): 256 frags; fi = ((row&63)>>4)*64 + q2*16 + (row&15)
// Fragment elem j: k = s*32 + q2*8 + j. Reader lane: quad=lane>>4 ↔ q2, nl=lane&15 ↔ row&15.

// ---------------- k_tn: tnbf = l2norm(tgt) bf16, 256-row-group fragment order ----------------
__global__ __launch_bounds__(64) void k_tn(const float* __restrict__ tgt,
                                           bf16* __restrict__ tnbf) {
  int row = blockIdx.x;            // b*256 + slot
  int b = row >> 8, slot = row & 255;
  int lane = threadIdx.x;
  const float* src = tgt + (size_t)row * Dd + lane * 4;
  float v[4];
#pragma unroll
  for (int u = 0; u < 4; u++) v[u] = src[u];
  float ss = v[0] * v[0] + v[1] * v[1] + v[2] * v[2] + v[3] * v[3];
#pragma unroll
  for (int m = 32; m >= 1; m >>= 1) ss += __shfl_xor(ss, m, 64);
  float inv = 1.0f / fmaxf(sqrtf(ss), NORM_EPSf);
  bf16 o[4] __attribute__((aligned(8)));
#pragma unroll
  for (int u = 0; u < 4; u++) o[u] = f2b(v[u] * inv);
  int s = lane >> 3;
  int q2 = (lane >> 1) & 3;
  int jh = (lane & 1) * 4;
  size_t fi = (size_t)((slot >> 4) * 64 + q2 * 16 + (slot & 15));
  *(float2*)(tnbf + ((size_t)(b * 8 + s) * 1024 + fi) * 8 + jh) = *(float2*)o;
}

// ---------------- k_prew1: w1 (DFFxD fp32) -> 64-row-group fragment order bf16 ----------------
__global__ __launch_bounds__(64) void k_prew1(const float* __restrict__ w1,
                                              bf16* __restrict__ w1bf) {
  int f = blockIdx.x;              // 0..2047
  int lane = threadIdx.x;
  const float* src = w1 + (size_t)f * Dd + lane * 4;
  bf16 o[4] __attribute__((aligned(8)));
#pragma unroll
  for (int u = 0; u < 4; u++) o[u] = f2b(src[u]);
  int s = lane >> 3;
  int q2 = (lane >> 1) & 3;
  int jh = (lane & 1) * 4;
  size_t fi = (size_t)(((f & 63) >> 4) * 64 + q2 * 16 + (f & 15));
  *(float2*)(w1bf + ((size_t)((f >> 6) * 8 + s) * 256 + fi) * 8 + jh) = *(float2*)o;
}

// ---------------- k_prew2: w2 (DxDFF fp32) -> 64-row-group fragment order (64 f-steps) ----------------
__global__ __launch_bounds__(64) void k_prew2(const float* __restrict__ w2,
                                              bf16* __restrict__ w2bf) {
  int d = blockIdx.x;              // 0..255
  int lane = threadIdx.x;          // sg = lane (f-step)
  const float* src = w2 + (size_t)d * Ff + lane * 32;
  size_t gbase = (size_t)((d >> 6) * 64 + lane) * 256;
  int fbase = ((d & 63) >> 4) * 64 + (d & 15);
#pragma unroll
  for (int q2 = 0; q2 < 4; q2++) {
    float4 v0 = *(const float4*)(src + q2 * 8);
    float4 v1 = *(const float4*)(src + q2 * 8 + 4);
    bf16 o[8] __attribute__((aligned(16)));
    o[0] = f2b(v0.x); o[1] = f2b(v0.y); o[2] = f2b(v0.z); o[3] = f2b(v0.w);
    o[4] = f2b(v1.x); o[5] = f2b(v1.y); o[6] = f2b(v1.z); o[7] = f2b(v1.w);
    *(float4*)(w2bf + (gbase + fbase + q2 * 16) * 8) = *(float4*)o;
  }
}

#define MFMA16(a, b, c) __builtin_amdgcn_mfma_f32_16x16x32_bf16(a, b, c, 0, 0, 0)

// ---------------- k_dots (MFMA, fused x-norm, pipelined): softmax(slots) -> attn_t, xb, S ----------------
__global__ __launch_bounds__(256) void k_dots(const bf16* __restrict__ tnbf,
                                              const float* __restrict__ x,
                                              bf16* __restrict__ xb,
                                              bf16* __restrict__ attn_t,
                                              float* __restrict__ S) {
  __shared__ __align__(16) bf16 Bs[2][4 * 520];   // double-buffered B fragments
  __shared__ float ssred[64 * 17];
  __shared__ float nxl[64];
  __shared__ float red[512];
  int b = blockIdx.x >> 6;
  int hw0 = (blockIdx.x & 63) * 64;
  int tid = threadIdx.x;
  int wave = tid >> 6, lane = tid & 63;
  int quad = lane >> 4, nl = lane & 15;

  int dp = tid >> 4;           // 0..15
  int ch = tid & 15;           // 0..15
  int qb = dp >> 2;
  int jb = (dp & 3) * 2;

  f32x4 acc[4][4];
#pragma unroll
  for (int i = 0; i < 4; i++)
#pragma unroll
    for (int j = 0; j < 4; j++) acc[i][j] = (f32x4){0.f, 0.f, 0.f, 0.f};
  float ssp[4] = {0.f, 0.f, 0.f, 0.f};

  // prologue prefetch: x-tile and A-fragments for s=0
  float4 va, vb;
  short8 afp[4];
  {
    const float* xr0 = x + (size_t)((b << 8) + 2 * dp) * HWw + hw0 + ch * 4;
    va = *(const float4*)xr0;
    vb = *(const float4*)(xr0 + HWw);
    const bf16* ts0 = tnbf + (size_t)(b * 8) * 1024 * 8;
#pragma unroll
    for (int mt = 0; mt < 4; mt++)
      afp[mt] = *(const short8*)(ts0 + (size_t)(((wave << 2) + mt) * 64 + lane) * 8);
  }

  for (int s = 0; s < 8; s++) {
    bf16* bsb = &Bs[s & 1][0];
    {
      float vva[4] = {va.x, va.y, va.z, va.w};
      float vvb[4] = {vb.x, vb.y, vb.z, vb.w};
      bf16 pa[4] __attribute__((aligned(8)));
      bf16 pb[4] __attribute__((aligned(8)));
#pragma unroll
      for (int jj = 0; jj < 4; jj++) {
        ssp[jj] += vva[jj] * vva[jj] + vvb[jj] * vvb[jj];
        pa[jj] = f2b(vva[jj]);
        pb[jj] = f2b(vvb[jj]);
      }
      bf16* xw = xb + (size_t)((b << 8) + s * 32 + 2 * dp) * HWw + hw0 + ch * 4;
      *(float2*)xw = *(float2*)pa;
      *(float2*)(xw + HWw) = *(float2*)pb;
#pragma unroll
      for (int jj = 0; jj < 4; jj++) {
        int hwl = ch * 4 + jj;
        int nt = hwl >> 4;
        int li = (qb << 4) | (hwl & 15);
        union { bf16 h[2]; unsigned int u; } pk;
        pk.h[0] = pa[jj];
        pk.h[1] = pb[jj];
        *(unsigned int*)&bsb[nt * 520 + li * 8 + jb] = pk.u;
      }
    }
    __syncthreads();
    short8 af[4];
#pragma unroll
    for (int mt = 0; mt < 4; mt++) af[mt] = afp[mt];
    if (s < 7) {
      // prefetch next step's x-tile and A-frags: in flight during this step's MFMAs
      const float* xr = x + (size_t)((b << 8) + (s + 1) * 32 + 2 * dp) * HWw + hw0 + ch * 4;
      va = *(const float4*)xr;
      vb = *(const float4*)(xr + HWw);
      const bf16* tsrc = tnbf + (size_t)(b * 8 + s + 1) * 1024 * 8;
#pragma unroll
      for (int mt = 0; mt < 4; mt++)
        afp[mt] = *(const short8*)(tsrc + (size_t)(((wave << 2) + mt) * 64 + lane) * 8);
    }
    short8 bfv[4];
#pragma unroll
    for (int nt = 0; nt < 4; nt++)
      bfv[nt] = *(const short8*)(bsb + nt * 520 + lane * 8);
#pragma unroll
    for (int mt = 0; mt < 4; mt++)
#pragma unroll
      for (int nt = 0; nt < 4; nt++) acc[mt][nt] = MFMA16(af[mt], bfv[nt], acc[mt][nt]);
  }

#pragma unroll
  for (int jj = 0; jj < 4; jj++) ssred[(ch * 4 + jj) * 17 + dp] = ssp[jj];
  __syncthreads();
  if (tid < 64) {
    float sum = 0.f;
#pragma unroll
    for (int i = 0; i < 16; i++) sum += ssred[tid * 17 + i];
    nxl[tid] = TEMP_INV / fmaxf(sqrtf(sum), NORM_EPSf);
  }
  __syncthreads();

  float sc[4];
#pragma unroll
  for (int nt = 0; nt < 4; nt++) sc[nt] = nxl[nt * 16 + nl];
#pragma unroll
  for (int mt = 0; mt < 4; mt++)
#pragma unroll
    for (int nt = 0; nt < 4; nt++)
#pragma unroll
      for (int r = 0; r < 4; r++) acc[mt][nt][r] *= sc[nt];

  float* red2 = red + 256;

  float pmax[4];
#pragma unroll
  for (int nt = 0; nt < 4; nt++) {
    float m = acc[0][nt][0];
#pragma unroll
    for (int mt = 0; mt < 4; mt++)
#pragma unroll
      for (int r = 0; r < 4; r++) m = fmaxf(m, acc[mt][nt][r]);
    m = fmaxf(m, __shfl_xor(m, 16, 64));
    m = fmaxf(m, __shfl_xor(m, 32, 64));
    pmax[nt] = m;
  }
  if (lane < 16) {
#pragma unroll
    for (int nt = 0; nt < 4; nt++) red[((wave << 2) + nt) * 16 + nl] = pmax[nt];
  }
  __syncthreads();
  float cmax[4];
#pragma unroll
  for (int nt = 0; nt < 4; nt++) {
    float m = red[nt * 16 + nl];
#pragma unroll
    for (int w2 = 1; w2 < 4; w2++) m = fmaxf(m, red[((w2 << 2) + nt) * 16 + nl]);
    cmax[nt] = m;
  }

  float psum[4];
#pragma unroll
  for (int nt = 0; nt < 4; nt++) {
    float s = 0.f;
#pragma unroll
    for (int mt = 0; mt < 4; mt++)
#pragma unroll
      for (int r = 0; r < 4; r++) {
        float e = __expf(acc[mt][nt][r] - cmax[nt]);
        acc[mt][nt][r] = e;
        s += e;
      }
    s += __shfl_xor(s, 16, 64);
    s += __shfl_xor(s, 32, 64);
    psum[nt] = s;
  }
  if (lane < 16) {
#pragma unroll
    for (int nt = 0; nt < 4; nt++) red2[((wave << 2) + nt) * 16 + nl] = psum[nt];
  }
  __syncthreads();
  float ci[4];
#pragma unroll
  for (int nt = 0; nt < 4; nt++) {
    float s = 0.f;
#pragma unroll
    for (int w2 = 0; w2 < 4; w2++) s += red2[((w2 << 2) + nt) * 16 + nl];
    ci[nt] = 1.0f / s;
  }

#pragma unroll
  for (int mt = 0; mt < 4; mt++) {
    int slotg = (b << 8) + (wave << 6) + (mt << 4) + (quad << 2);
#pragma unroll
    for (int r = 0; r < 4; r++) {
      size_t base = (size_t)(slotg + r) * HWw + hw0;
      float rs = 0.f;
#pragma unroll
      for (int nt = 0; nt < 4; nt++) {
        float a = acc[mt][nt][r] * ci[nt] + EPSf;
        bf16 hb = f2b(a);
        attn_t[base + nt * 16 + nl] = hb;
        rs += b2f(hb);
      }
      rs += __shfl_xor(rs, 1, 64);
      rs += __shfl_xor(rs, 2, 64);
      rs += __shfl_xor(rs, 4, 64);
      rs += __shfl_xor(rs, 8, 64);
      if (nl == 0) atomicAdd(&S[slotg + r], rs);
    }
  }
}

// ---------------- LDS tile helper (64x32 bf16, fragment order) ----------------
static __device__ __forceinline__ void stage_bf16_tile(const bf16* __restrict__ src, int ld,
                                                       bf16* __restrict__ dst, int tid) {
  int r = (tid & 15) | ((tid >> 6) << 4);
  int q = (tid >> 4) & 3;
  float4 v = *(const float4*)(src + (size_t)r * ld + q * 8);
  *(float4*)(dst + (size_t)(((r >> 4) << 6) | (q << 4) | (r & 15)) * 8) = v;
}

// ---------------- GEMM2 (MFMA, 128x128 tile, hsplit=8 + atomic): t2 += attn_t . xb^T ----------------
// grid 1024: b = n&31 (keeps all 32 blocks of a batch on one XCD -> 4 MB L2-resident slice)
__global__ __launch_bounds__(256) void k_gemm2(const bf16* __restrict__ attn_t,
                                               const bf16* __restrict__ xb,
                                               float* __restrict__ t2) {
  __shared__ __align__(16) bf16 As2[2][64 * 32];
  __shared__ __align__(16) bf16 Bs2[2][64 * 32];
  int n = blockIdx.x;
  int b = n & 31;
  int r2 = n >> 5;                 // 0..31
  int k0 = (r2 & 1) * 128;
  int d0 = ((r2 >> 1) & 1) * 128;
  int h0b = (r2 >> 2) * 512;       // hs 0..7
  int tid = threadIdx.x;
  int wave = tid >> 6, lane = tid & 63;
  int wr = wave >> 1, wc = wave & 1;

  f32x4 acc[4][4];
#pragma unroll
  for (int i = 0; i < 4; i++)
#pragma unroll
    for (int j = 0; j < 4; j++) acc[i][j] = (f32x4){0.f, 0.f, 0.f, 0.f};

  const bf16* Ap = attn_t + (size_t)((b << 8) + k0) * HWw + h0b;
  const bf16* Bp = xb + (size_t)((b << 8) + d0) * HWw + h0b;
  for (int h0 = 0; h0 < 512; h0 += 32) {
    stage_bf16_tile(Ap + h0, HWw, As2[0], tid);
    stage_bf16_tile(Ap + (size_t)64 * HWw + h0, HWw, As2[1], tid);
    stage_bf16_tile(Bp + h0, HWw, Bs2[0], tid);
    stage_bf16_tile(Bp + (size_t)64 * HWw + h0, HWw, Bs2[1], tid);
    __syncthreads();
    short8 af[4], bfr[4];
#pragma unroll
    for (int mt = 0; mt < 4; mt++)
      af[mt] = *(const short8*)(&As2[wr][(size_t)(mt * 64 + lane) * 8]);
#pragma unroll
    for (int nt = 0; nt < 4; nt++)
      bfr[nt] = *(const short8*)(&Bs2[wc][(size_t)(nt * 64 + lane) * 8]);
#pragma unroll
    for (int mt = 0; mt < 4; mt++)
#pragma unroll
      for (int nt = 0; nt < 4; nt++) acc[mt][nt] = MFMA16(af[mt], bfr[nt], acc[mt][nt]);
    __syncthreads();
  }
  int quad = lane >> 4, nl = lane & 15;
#pragma unroll
  for (int mt = 0; mt < 4; mt++)
#pragma unroll
    for (int r = 0; r < 4; r++) {
      int row = (b << 8) + k0 + wr * 64 + mt * 16 + quad * 4 + r;
#pragma unroll
      for (int nt = 0; nt < 4; nt++) {
        int col = d0 + wc * 64 + nt * 16 + nl;
        atomicAdd(&t2[(size_t)row * Dd + col], acc[mt][nt][r]);
      }
    }
}

// ---------------- LN_pre: t = LN(t2/S + tgt); also tbf (64-row-group fragment order) ----------------
__global__ __launch_bounds__(64) void k_ln_pre(const float* __restrict__ t2,
                                               const float* __restrict__ S,
                                               const float* __restrict__ tgt,
                                               const float* __restrict__ g,
                                               const float* __restrict__ be,
                                               float* __restrict__ t,
                                               bf16* __restrict__ tbf) {
  int row = blockIdx.x;
  int lane = threadIdx.x;
  float sInv = 1.0f / S[row];
  const float* p2 = t2 + (size_t)row * Dd + lane * 4;
  const float* pt = tgt + (size_t)row * Dd + lane * 4;
  float v[4];
#pragma unroll
  for (int u = 0; u < 4; u++) v[u] = p2[u] * sInv + pt[u];
  float s1 = v[0] + v[1] + v[2] + v[3];
  float s2 = v[0] * v[0] + v[1] * v[1] + v[2] * v[2] + v[3] * v[3];
#pragma unroll
  for (int m = 32; m >= 1; m >>= 1) {
    s1 += __shfl_xor(s1, m, 64);
    s2 += __shfl_xor(s2, m, 64);
  }
  float mu = s1 * (1.0f / 256.0f);
  float var = s2 * (1.0f / 256.0f) - mu * mu;
  float rs = rsqrtf(fmaxf(var, 0.f) + LN_EPSf);
  float* po = t + (size_t)row * Dd + lane * 4;
  bf16 o[4] __attribute__((aligned(8)));
#pragma unroll
  for (int u = 0; u < 4; u++) {
    float val = (v[u] - mu) * rs * g[lane * 4 + u] + be[lane * 4 + u];
    po[u] = val;
    o[u] = f2b(val);
  }
  int s = lane >> 3;
  int q2 = (lane >> 1) & 3;
  int jh = (lane & 1) * 4;
  size_t fi = (size_t)(((row & 63) >> 4) * 64 + q2 * 16 + (row & 15));
  *(float2*)(tbf + ((size_t)((row >> 6) * 8 + s) * 256 + fi) * 8 + jh) = *(float2*)o;
}

// ---------------- FFN GEMM3 (MFMA, zero-LDS): h1 = relu(tbf @ w1bf^T + b1) ----------------
__global__ __launch_bounds__(256) void k_ffn1(const bf16* __restrict__ tbf,
                                              const bf16* __restrict__ w1bf,
                                              const float* __restrict__ b1,
                                              bf16* __restrict__ h1) {
  int rowgrp = blockIdx.x >> 5;    // 0..127
  int fgrp = blockIdx.x & 31;      // 0..31
  int tid = threadIdx.x;
  int wave = tid >> 6, lane = tid & 63;
  int am = (wave >> 1) * 2, bn = (wave & 1) * 2;

  f32x4 acc[2][2];
#pragma unroll
  for (int i = 0; i < 2; i++)
#pragma unroll
    for (int j = 0; j < 2; j++) acc[i][j] = (f32x4){0.f, 0.f, 0.f, 0.f};

  const bf16* Abase = tbf + (size_t)rowgrp * 8 * 256 * 8;
  const bf16* Bbase = w1bf + (size_t)fgrp * 8 * 256 * 8;
#pragma unroll
  for (int s = 0; s < 8; s++) {
    short8 af[2], bfr[2];
#pragma unroll
    for (int i = 0; i < 2; i++)
      af[i] = *(const short8*)(Abase + ((size_t)s * 256 + ((am + i) * 64 + lane)) * 8);
#pragma unroll
    for (int j = 0; j < 2; j++)
      bfr[j] = *(const short8*)(Bbase + ((size_t)s * 256 + ((bn + j) * 64 + lane)) * 8);
#pragma unroll
    for (int i = 0; i < 2; i++)
#pragma unroll
      for (int j = 0; j < 2; j++) acc[i][j] = MFMA16(af[i], bfr[j], acc[i][j]);
  }
  int quad = lane >> 4, nl = lane & 15;
  int row0 = rowgrp * 64, f0 = fgrp * 64;
#pragma unroll
  for (int j = 0; j < 2; j++) {
    int f = f0 + (bn + j) * 16 + nl;
    float bias = b1[f];
#pragma unroll
    for (int i = 0; i < 2; i++)
#pragma unroll
      for (int r = 0; r < 4; r++) {
        int row = row0 + (am + i) * 16 + quad * 4 + r;
        h1[(size_t)row * Ff + f] = f2b(fmaxf(acc[i][j][r] + bias, 0.f));
      }
  }
}

// ---------------- FFN GEMM4 (MFMA, N=256, ksp=8 + atomic): o2 += h1 @ w2^T ----------------
// wave = d-group (64 cols each); h1 read exactly once; B direct-global fragment order.
__global__ __launch_bounds__(256) void k_ffn2(const bf16* __restrict__ h1,
                                              const bf16* __restrict__ w2bf,
                                              float* __restrict__ o2) {
  __shared__ __align__(16) bf16 As[64 * 32];
  int n = blockIdx.x;
  int rowgrp = n >> 3;             // 0..127
  int ksp = n & 7;                 // 0..7
  int tid = threadIdx.x;
  int wave = tid >> 6, lane = tid & 63;

  f32x4 acc[4][4];
#pragma unroll
  for (int i = 0; i < 4; i++)
#pragma unroll
    for (int j = 0; j < 4; j++) acc[i][j] = (f32x4){0.f, 0.f, 0.f, 0.f};

  const bf16* Ap = h1 + (size_t)(rowgrp * 64) * Ff + ksp * 256;
  const bf16* Bbase = w2bf + (size_t)(wave * 64) * 256 * 8;
  for (int st = 0; st < 8; st++) {
    int sg = ksp * 8 + st;
    stage_bf16_tile(Ap + st * 32, Ff, As, tid);
    __syncthreads();
    short8 af[4], bfr[4];
#pragma unroll
    for (int mt = 0; mt < 4; mt++)
      af[mt] = *(const short8*)(As + (size_t)(mt * 64 + lane) * 8);
#pragma unroll
    for (int nt = 0; nt < 4; nt++)
      bfr[nt] = *(const short8*)(Bbase + ((size_t)sg * 256 + (nt * 64 + lane)) * 8);
#pragma unroll
    for (int mt = 0; mt < 4; mt++)
#pragma unroll
      for (int nt = 0; nt < 4; nt++) acc[mt][nt] = MFMA16(af[mt], bfr[nt], acc[mt][nt]);
    __syncthreads();
  }
  int quad = lane >> 4, nl = lane & 15;
#pragma unroll
  for (int mt = 0; mt < 4; mt++)
#pragma unroll
    for (int r = 0; r < 4; r++) {
      int row = rowgrp * 64 + mt * 16 + quad * 4 + r;
#pragma unroll
      for (int nt = 0; nt < 4; nt++) {
        int col = wave * 64 + nt * 16 + nl;
        atomicAdd(&o2[(size_t)row * Dd + col], acc[mt][nt][r]);
      }
    }
}

// ---------------- LN_out: out = LN(o2 + b2 + t) with g3/be3 ----------------
__global__ __launch_bounds__(64) void k_ln_out(const float* __restrict__ o2,
                                               const float* __restrict__ b2v,
                                               const float* __restrict__ t,
                                               const float* __restrict__ g,
                                               const float* __restrict__ be,
                                               float* __restrict__ out) {
  int row = blockIdx.x;
  int lane = threadIdx.x;
  const float* po = o2 + (size_t)row * Dd + lane * 4;
  const float* pt = t + (size_t)row * Dd + lane * 4;
  float v[4];
#pragma unroll
  for (int u = 0; u < 4; u++) v[u] = po[u] + b2v[lane * 4 + u] + pt[u];
  float s1 = v[0] + v[1] + v[2] + v[3];
  float s2 = v[0] * v[0] + v[1] * v[1] + v[2] * v[2] + v[3] * v[3];
#pragma unroll
  for (int m = 32; m >= 1; m >>= 1) {
    s1 += __shfl_xor(s1, m, 64);
    s2 += __shfl_xor(s2, m, 64);
  }
  float mu = s1 * (1.0f / 256.0f);
  float var = s2 * (1.0f / 256.0f) - mu * mu;
  float rs = rsqrtf(fmaxf(var, 0.f) + LN_EPSf);
  float* pw = out + (size_t)row * Dd + lane * 4;
#pragma unroll
  for (int u = 0; u < 4; u++)
    pw[u] = (v[u] - mu) * rs * g[lane * 4 + u] + be[lane * 4 + u];
}

extern "C" void kernel_launch(void* const* d_in, const int* in_sizes, int n_in,
                              void* d_out, int out_size, void* d_ws, size_t ws_size,
                              hipStream_t stream) {
  const float* x = (const float*)d_in[0];
  const float* tgt = (const float*)d_in[1];
  const float* w1 = (const float*)d_in[2];
  const float* b1 = (const float*)d_in[3];
  const float* w2 = (const float*)d_in[4];
  const float* b2v = (const float*)d_in[5];
  const float* g2 = (const float*)d_in[6];
  const float* be2 = (const float*)d_in[7];
  const float* g3 = (const float*)d_in[8];
  const float* be3 = (const float*)d_in[9];
  float* out = (float*)d_out;

  // Aliasing (R8-proven): tbf->tnbf (dead after k_dots); o2->t2 (dead after ln_pre,
  // re-zeroed); w1bf/w2bf carved from attn_t (dead after gemm2; prew after gemm2).
  char* w = (char*)d_ws;
  bf16* tnbf = (bf16*)w;     w += (size_t)Bb * Kk * Dd * 2;   // 4 MB
  float* S = (float*)w;      w += (size_t)Bb * Kk * 4;        // 32 KB
  float* t = (float*)w;      w += (size_t)Bb * Kk * Dd * 4;   // 8 MB
  float* t2 = (float*)w;     w += (size_t)Bb * Kk * Dd * 4;   // 8 MB
  bf16* attn_t = (bf16*)w;   w += (size_t)Bb * HWw * Kk * 2;  // 64 MB
  bf16* h1 = (bf16*)w;       w += (size_t)Bb * Kk * Ff * 2;   // 32 MB
  bf16* xb = (bf16*)w;       w += (size_t)Bb * Dd * HWw * 2;  // 64 MB

  bf16* tbf = tnbf;                      // 4 MB alias
  float* o2 = t2;                        // 8 MB alias
  bf16* w1bf = attn_t;                   // 1 MB carve
  bf16* w2bf = attn_t + (size_t)Ff * Dd; // 1 MB carve

  hipMemsetAsync(S, 0, (size_t)Bb * Kk * 4, stream);
  hipMemsetAsync(t2, 0, (size_t)Bb * Kk * Dd * 4, stream);
  k_tn<<<Bb * Kk, 64, 0, stream>>>(tgt, tnbf);
  k_dots<<<Bb * (HWw / 64), 256, 0, stream>>>(tnbf, x, xb, attn_t, S);
  k_gemm2<<<1024, 256, 0, stream>>>(attn_t, xb, t2);
  k_prew1<<<Ff, 64, 0, stream>>>(w1, w1bf);
  k_prew2<<<Dd, 64, 0, stream>>>(w2, w2bf);
  k_ln_pre<<<Bb * Kk, 64, 0, stream>>>(t2, S, tgt, g2, be2, t, tbf);
  hipMemsetAsync(o2, 0, (size_t)Bb * Kk * Dd * 4, stream);
  k_ffn1<<<(Bb * Kk / 64) * (Ff / 64), 256, 0, stream>>>(tbf, w1bf, b1, h1);
  k_ffn2<<<(Bb * Kk / 64) * 8, 256, 0, stream>>>(h1, w2bf, o2);
  k_ln_out<<<Bb * Kk, 64, 0, stream>>>(o2, b2v, t, g3, be3, out);
}

// Round 10
// 448.372 us; speedup vs baseline: 3.2935x; 1.0262x over previous
//
#include <hip/hip_runtime.h>
#include <hip/hip_bf16.h>

using bf16 = __hip_bfloat16;

typedef __attribute__((ext_vector_type(8))) short short8;
typedef __attribute__((ext_vector_type(4))) float f32x4;

constexpr int Bb = 32, Dd = 256, HWw = 4096, Kk = 256, Ff = 2048;
constexpr float TEMP_INV = 1.0f / 0.07f;
constexpr float EPSf = 1e-6f;
constexpr float NORM_EPSf = 1e-12f;
constexpr float LN_EPSf = 1e-5f;

static __device__ __forceinline__ float b2f(bf16 v) { return __bfloat162float(v); }
static __device__ __forceinline__ bf16 f2b(float v) { return __float2bfloat16(v); }

// Fragment-order conventions (16x16x32 MFMA, K-step 32):
//   element (row, k): s' = k>>5, q2 = (k>>3)&3, j = k&7
//   256-row group (tnbf, attn_bf, xb_bf): fi = (row>>4)*64 + q2*16 + (row&15); 1024 frags/step
//   64-row group (tbf/w1bf/w2bf/h1bf):    fi = ((row&63)>>4)*64 + q2*16 + (row&15); 256 frags/step
// Reader identity: addr = set_base + (mtile_local*64 + lane)*8  (lane = q2*16 + row&15)

// ---------------- k_tn: tnbf = l2norm(tgt) bf16, 256-row-group fragment order ----------------
__global__ __launch_bounds__(64) void k_tn(const float* __restrict__ tgt,
                                           bf16* __restrict__ tnbf) {
  int row = blockIdx.x;            // b*256 + slot
  int b = row >> 8, slot = row & 255;
  int lane = threadIdx.x;
  const float* src = tgt + (size_t)row * Dd + lane * 4;
  float v[4];
#pragma unroll
  for (int u = 0; u < 4; u++) v[u] = src[u];
  float ss = v[0] * v[0] + v[1] * v[1] + v[2] * v[2] + v[3] * v[3];
#pragma unroll
  for (int m = 32; m >= 1; m >>= 1) ss += __shfl_xor(ss, m, 64);
  float inv = 1.0f / fmaxf(sqrtf(ss), NORM_EPSf);
  bf16 o[4] __attribute__((aligned(8)));
#pragma unroll
  for (int u = 0; u < 4; u++) o[u] = f2b(v[u] * inv);
  int s = lane >> 3;
  int q2 = (lane >> 1) & 3;
  int jh = (lane & 1) * 4;
  size_t fi = (size_t)((slot >> 4) * 64 + q2 * 16 + (slot & 15));
  *(float2*)(tnbf + ((size_t)(b * 8 + s) * 1024 + fi) * 8 + jh) = *(float2*)o;
}

// ---------------- k_prew1: w1 (DFFxD fp32) -> 64-row-group fragment order bf16 ----------------
__global__ __launch_bounds__(64) void k_prew1(const float* __restrict__ w1,
                                              bf16* __restrict__ w1bf) {
  int f = blockIdx.x;              // 0..2047
  int lane = threadIdx.x;
  const float* src = w1 + (size_t)f * Dd + lane * 4;
  bf16 o[4] __attribute__((aligned(8)));
#pragma unroll
  for (int u = 0; u < 4; u++) o[u] = f2b(src[u]);
  int s = lane >> 3;
  int q2 = (lane >> 1) & 3;
  int jh = (lane & 1) * 4;
  size_t fi = (size_t)(((f & 63) >> 4) * 64 + q2 * 16 + (f & 15));
  *(float2*)(w1bf + ((size_t)((f >> 6) * 8 + s) * 256 + fi) * 8 + jh) = *(float2*)o;
}

// ---------------- k_prew2: w2 (DxDFF fp32) -> 64-row-group fragment order (64 f-steps) ----------------
__global__ __launch_bounds__(64) void k_prew2(const float* __restrict__ w2,
                                              bf16* __restrict__ w2bf) {
  int d = blockIdx.x;              // 0..255
  int lane = threadIdx.x;          // sg = lane (f-step)
  const float* src = w2 + (size_t)d * Ff + lane * 32;
  size_t gbase = (size_t)((d >> 6) * 64 + lane) * 256;
  int fbase = ((d & 63) >> 4) * 64 + (d & 15);
#pragma unroll
  for (int q2 = 0; q2 < 4; q2++) {
    float4 v0 = *(const float4*)(src + q2 * 8);
    float4 v1 = *(const float4*)(src + q2 * 8 + 4);
    bf16 o[8] __attribute__((aligned(16)));
    o[0] = f2b(v0.x); o[1] = f2b(v0.y); o[2] = f2b(v0.z); o[3] = f2b(v0.w);
    o[4] = f2b(v1.x); o[5] = f2b(v1.y); o[6] = f2b(v1.z); o[7] = f2b(v1.w);
    *(float4*)(w2bf + (gbase + fbase + q2 * 16) * 8) = *(float4*)o;
  }
}

#define MFMA16(a, b, c) __builtin_amdgcn_mfma_f32_16x16x32_bf16(a, b, c, 0, 0, 0)

// ---------------- k_dots: softmax(slots) -> attn_bf (frag order), xb_bf (frag order), S ----------------
__global__ __launch_bounds__(256) void k_dots(const bf16* __restrict__ tnbf,
                                              const float* __restrict__ x,
                                              bf16* __restrict__ xb_bf,
                                              bf16* __restrict__ attn_bf,
                                              float* __restrict__ S) {
  __shared__ __align__(16) bf16 Bs[2][4 * 520];   // double-buffered B fragments
  __shared__ float ssred[64 * 17];
  __shared__ float nxl[64];
  __shared__ float red[512];
  int b = blockIdx.x >> 6;
  int hw0 = (blockIdx.x & 63) * 64;
  int tid = threadIdx.x;
  int wave = tid >> 6, lane = tid & 63;
  int quad = lane >> 4, nl = lane & 15;

  int dp = tid >> 4;           // 0..15
  int ch = tid & 15;           // 0..15
  int qb = dp >> 2;
  int jb = (dp & 3) * 2;

  f32x4 acc[4][4];
#pragma unroll
  for (int i = 0; i < 4; i++)
#pragma unroll
    for (int j = 0; j < 4; j++) acc[i][j] = (f32x4){0.f, 0.f, 0.f, 0.f};
  float ssp[4] = {0.f, 0.f, 0.f, 0.f};

  // xb_bf write coords for this thread (per step s, rows d=s*32+2dp, +1)
  int spx = (hw0 >> 5) + (ch >> 3);       // s' local to b
  int q2x = (ch >> 1) & 3;
  int jx = (ch & 1) * 4;

  // prologue prefetch: x-tile and A-fragments for s=0
  float4 va, vb;
  short8 afp[4];
  {
    const float* xr0 = x + (size_t)((b << 8) + 2 * dp) * HWw + hw0 + ch * 4;
    va = *(const float4*)xr0;
    vb = *(const float4*)(xr0 + HWw);
    const bf16* ts0 = tnbf + (size_t)(b * 8) * 1024 * 8;
#pragma unroll
    for (int mt = 0; mt < 4; mt++)
      afp[mt] = *(const short8*)(ts0 + (size_t)(((wave << 2) + mt) * 64 + lane) * 8);
  }

  for (int s = 0; s < 8; s++) {
    bf16* bsb = &Bs[s & 1][0];
    {
      float vva[4] = {va.x, va.y, va.z, va.w};
      float vvb[4] = {vb.x, vb.y, vb.z, vb.w};
      bf16 pa[4] __attribute__((aligned(8)));
      bf16 pb[4] __attribute__((aligned(8)));
#pragma unroll
      for (int jj = 0; jj < 4; jj++) {
        ssp[jj] += vva[jj] * vva[jj] + vvb[jj] * vvb[jj];
        pa[jj] = f2b(vva[jj]);
        pb[jj] = f2b(vvb[jj]);
      }
      // xb_bf fragment-order store (8B each, two adjacent d-rows)
      int d0r = s * 32 + 2 * dp;
      int fiA = (d0r >> 4) * 64 + q2x * 16 + (d0r & 15);
      size_t base = ((size_t)(b * 128) + spx) * 1024;
      *(float2*)(xb_bf + (base + fiA) * 8 + jx) = *(float2*)pa;
      *(float2*)(xb_bf + (base + fiA + 1) * 8 + jx) = *(float2*)pb;
#pragma unroll
      for (int jj = 0; jj < 4; jj++) {
        int hwl = ch * 4 + jj;
        int nt = hwl >> 4;
        int li = (qb << 4) | (hwl & 15);
        union { bf16 h[2]; unsigned int u; } pk;
        pk.h[0] = pa[jj];
        pk.h[1] = pb[jj];
        *(unsigned int*)&bsb[nt * 520 + li * 8 + jb] = pk.u;
      }
    }
    __syncthreads();
    short8 af[4];
#pragma unroll
    for (int mt = 0; mt < 4; mt++) af[mt] = afp[mt];
    if (s < 7) {
      const float* xr = x + (size_t)((b << 8) + (s + 1) * 32 + 2 * dp) * HWw + hw0 + ch * 4;
      va = *(const float4*)xr;
      vb = *(const float4*)(xr + HWw);
      const bf16* tsrc = tnbf + (size_t)(b * 8 + s + 1) * 1024 * 8;
#pragma unroll
      for (int mt = 0; mt < 4; mt++)
        afp[mt] = *(const short8*)(tsrc + (size_t)(((wave << 2) + mt) * 64 + lane) * 8);
    }
    short8 bfv[4];
#pragma unroll
    for (int nt = 0; nt < 4; nt++)
      bfv[nt] = *(const short8*)(bsb + nt * 520 + lane * 8);
#pragma unroll
    for (int mt = 0; mt < 4; mt++)
#pragma unroll
      for (int nt = 0; nt < 4; nt++) acc[mt][nt] = MFMA16(af[mt], bfv[nt], acc[mt][nt]);
  }

#pragma unroll
  for (int jj = 0; jj < 4; jj++) ssred[(ch * 4 + jj) * 17 + dp] = ssp[jj];
  __syncthreads();
  if (tid < 64) {
    float sum = 0.f;
#pragma unroll
    for (int i = 0; i < 16; i++) sum += ssred[tid * 17 + i];
    nxl[tid] = TEMP_INV / fmaxf(sqrtf(sum), NORM_EPSf);
  }
  __syncthreads();

  float sc[4];
#pragma unroll
  for (int nt = 0; nt < 4; nt++) sc[nt] = nxl[nt * 16 + nl];
#pragma unroll
  for (int mt = 0; mt < 4; mt++)
#pragma unroll
    for (int nt = 0; nt < 4; nt++)
#pragma unroll
      for (int r = 0; r < 4; r++) acc[mt][nt][r] *= sc[nt];

  float* red2 = red + 256;

  float pmax[4];
#pragma unroll
  for (int nt = 0; nt < 4; nt++) {
    float m = acc[0][nt][0];
#pragma unroll
    for (int mt = 0; mt < 4; mt++)
#pragma unroll
      for (int r = 0; r < 4; r++) m = fmaxf(m, acc[mt][nt][r]);
    m = fmaxf(m, __shfl_xor(m, 16, 64));
    m = fmaxf(m, __shfl_xor(m, 32, 64));
    pmax[nt] = m;
  }
  if (lane < 16) {
#pragma unroll
    for (int nt = 0; nt < 4; nt++) red[((wave << 2) + nt) * 16 + nl] = pmax[nt];
  }
  __syncthreads();
  float cmax[4];
#pragma unroll
  for (int nt = 0; nt < 4; nt++) {
    float m = red[nt * 16 + nl];
#pragma unroll
    for (int w2 = 1; w2 < 4; w2++) m = fmaxf(m, red[((w2 << 2) + nt) * 16 + nl]);
    cmax[nt] = m;
  }

  float psum[4];
#pragma unroll
  for (int nt = 0; nt < 4; nt++) {
    float s = 0.f;
#pragma unroll
    for (int mt = 0; mt < 4; mt++)
#pragma unroll
      for (int r = 0; r < 4; r++) {
        float e = __expf(acc[mt][nt][r] - cmax[nt]);
        acc[mt][nt][r] = e;
        s += e;
      }
    s += __shfl_xor(s, 16, 64);
    s += __shfl_xor(s, 32, 64);
    psum[nt] = s;
  }
  if (lane < 16) {
#pragma unroll
    for (int nt = 0; nt < 4; nt++) red2[((wave << 2) + nt) * 16 + nl] = psum[nt];
  }
  __syncthreads();
  float ci[4];
#pragma unroll
  for (int nt = 0; nt < 4; nt++) {
    float s = 0.f;
#pragma unroll
    for (int w2 = 0; w2 < 4; w2++) s += red2[((w2 << 2) + nt) * 16 + nl];
    ci[nt] = 1.0f / s;
  }

  // ---- write attn in A-fragment order (for gemm2) + spatial sums S ----
  int jat = nl & 7;
#pragma unroll
  for (int mt = 0; mt < 4; mt++) {
    int slotg = (b << 8) + (wave << 6) + (mt << 4) + (quad << 2);
    int fiBase = ((wave << 2) + mt) * 64 + (quad << 2);
#pragma unroll
    for (int r = 0; r < 4; r++) {
      float rs = 0.f;
#pragma unroll
      for (int nt = 0; nt < 4; nt++) {
        float a = acc[mt][nt][r] * ci[nt] + EPSf;
        bf16 hb = f2b(a);
        int q2p = ((nt & 1) << 1) + (nl >> 3);
        size_t sp = (size_t)(b * 128) + (hw0 >> 5) + (nt >> 1);
        attn_bf[(sp * 1024 + fiBase + q2p * 16 + r) * 8 + jat] = hb;
        rs += b2f(hb);
      }
      rs += __shfl_xor(rs, 1, 64);
      rs += __shfl_xor(rs, 2, 64);
      rs += __shfl_xor(rs, 4, 64);
      rs += __shfl_xor(rs, 8, 64);
      if (nl == 0) atomicAdd(&S[slotg + r], rs);
    }
  }
}

// ---------------- GEMM2 (MFMA, zero-LDS, hsplit=4 + atomic): t2 += attn . xb^T ----------------
// Both operands direct-global in fragment order. b = n&31 -> all 64 blocks/batch on XCD b%8.
__global__ __launch_bounds__(256) void k_gemm2(const bf16* __restrict__ attn_bf,
                                               const bf16* __restrict__ xb_bf,
                                               float* __restrict__ t2) {
  int n = blockIdx.x;
  int b = n & 31;
  int r2 = n >> 5;                 // 0..63
  int kp = r2 & 3;                 // 64-slot tile
  int dgrp = (r2 >> 2) & 3;        // 64-d tile
  int hs = r2 >> 4;                // 0..3 (1024 hw each)
  int tid = threadIdx.x;
  int wave = tid >> 6, lane = tid & 63;
  int wr = wave >> 1, wc = wave & 1;

  f32x4 acc[2][2];
#pragma unroll
  for (int i = 0; i < 2; i++)
#pragma unroll
    for (int j = 0; j < 2; j++) acc[i][j] = (f32x4){0.f, 0.f, 0.f, 0.f};

  const bf16* Abase = attn_bf + ((size_t)(b * 128 + hs * 32) * 1024 + (size_t)(kp * 4 + wr * 2) * 64) * 8;
  const bf16* Bbase = xb_bf + ((size_t)(b * 128 + hs * 32) * 1024 + (size_t)(dgrp * 4 + wc * 2) * 64) * 8;
#pragma unroll 4
  for (int st = 0; st < 32; st++) {
    const bf16* Ap = Abase + (size_t)st * 1024 * 8;
    const bf16* Bp = Bbase + (size_t)st * 1024 * 8;
    short8 a0 = *(const short8*)(Ap + (size_t)lane * 8);
    short8 a1 = *(const short8*)(Ap + (size_t)(64 + lane) * 8);
    short8 b0 = *(const short8*)(Bp + (size_t)lane * 8);
    short8 b1 = *(const short8*)(Bp + (size_t)(64 + lane) * 8);
    acc[0][0] = MFMA16(a0, b0, acc[0][0]);
    acc[0][1] = MFMA16(a0, b1, acc[0][1]);
    acc[1][0] = MFMA16(a1, b0, acc[1][0]);
    acc[1][1] = MFMA16(a1, b1, acc[1][1]);
  }
  int quad = lane >> 4, nl = lane & 15;
#pragma unroll
  for (int i = 0; i < 2; i++)
#pragma unroll
    for (int r = 0; r < 4; r++) {
      int row = (b << 8) + kp * 64 + wr * 32 + i * 16 + quad * 4 + r;
#pragma unroll
      for (int j = 0; j < 2; j++) {
        int col = dgrp * 64 + wc * 32 + j * 16 + nl;
        atomicAdd(&t2[(size_t)row * Dd + col], acc[i][j][r]);
      }
    }
}

// ---------------- LN_pre: t = LN(t2/S + tgt); also tbf (64-row-group fragment order) ----------------
__global__ __launch_bounds__(64) void k_ln_pre(const float* __restrict__ t2,
                                               const float* __restrict__ S,
                                               const float* __restrict__ tgt,
                                               const float* __restrict__ g,
                                               const float* __restrict__ be,
                                               float* __restrict__ t,
                                               bf16* __restrict__ tbf) {
  int row = blockIdx.x;
  int lane = threadIdx.x;
  float sInv = 1.0f / S[row];
  const float* p2 = t2 + (size_t)row * Dd + lane * 4;
  const float* pt = tgt + (size_t)row * Dd + lane * 4;
  float v[4];
#pragma unroll
  for (int u = 0; u < 4; u++) v[u] = p2[u] * sInv + pt[u];
  float s1 = v[0] + v[1] + v[2] + v[3];
  float s2 = v[0] * v[0] + v[1] * v[1] + v[2] * v[2] + v[3] * v[3];
#pragma unroll
  for (int m = 32; m >= 1; m >>= 1) {
    s1 += __shfl_xor(s1, m, 64);
    s2 += __shfl_xor(s2, m, 64);
  }
  float mu = s1 * (1.0f / 256.0f);
  float var = s2 * (1.0f / 256.0f) - mu * mu;
  float rs = rsqrtf(fmaxf(var, 0.f) + LN_EPSf);
  float* po = t + (size_t)row * Dd + lane * 4;
  bf16 o[4] __attribute__((aligned(8)));
#pragma unroll
  for (int u = 0; u < 4; u++) {
    float val = (v[u] - mu) * rs * g[lane * 4 + u] + be[lane * 4 + u];
    po[u] = val;
    o[u] = f2b(val);
  }
  int s = lane >> 3;
  int q2 = (lane >> 1) & 3;
  int jh = (lane & 1) * 4;
  size_t fi = (size_t)(((row & 63) >> 4) * 64 + q2 * 16 + (row & 15));
  *(float2*)(tbf + ((size_t)((row >> 6) * 8 + s) * 256 + fi) * 8 + jh) = *(float2*)o;
}

// ---------------- FFN GEMM3 (MFMA, zero-LDS): h1bf = relu(tbf @ w1bf^T + b1), frag order ----------------
__global__ __launch_bounds__(256) void k_ffn1(const bf16* __restrict__ tbf,
                                              const bf16* __restrict__ w1bf,
                                              const float* __restrict__ b1,
                                              bf16* __restrict__ h1bf) {
  int rowgrp = blockIdx.x >> 5;    // 0..127
  int fgrp = blockIdx.x & 31;      // 0..31
  int tid = threadIdx.x;
  int wave = tid >> 6, lane = tid & 63;
  int am = (wave >> 1) * 2, bn = (wave & 1) * 2;

  f32x4 acc[2][2];
#pragma unroll
  for (int i = 0; i < 2; i++)
#pragma unroll
    for (int j = 0; j < 2; j++) acc[i][j] = (f32x4){0.f, 0.f, 0.f, 0.f};

  const bf16* Abase = tbf + (size_t)rowgrp * 8 * 256 * 8;
  const bf16* Bbase = w1bf + (size_t)fgrp * 8 * 256 * 8;
#pragma unroll
  for (int s = 0; s < 8; s++) {
    short8 af[2], bfr[2];
#pragma unroll
    for (int i = 0; i < 2; i++)
      af[i] = *(const short8*)(Abase + ((size_t)s * 256 + ((am + i) * 64 + lane)) * 8);
#pragma unroll
    for (int j = 0; j < 2; j++)
      bfr[j] = *(const short8*)(Bbase + ((size_t)s * 256 + ((bn + j) * 64 + lane)) * 8);
#pragma unroll
    for (int i = 0; i < 2; i++)
#pragma unroll
      for (int j = 0; j < 2; j++) acc[i][j] = MFMA16(af[i], bfr[j], acc[i][j]);
  }
  int quad = lane >> 4, nl = lane & 15;
  int jat = nl & 7;
#pragma unroll
  for (int j = 0; j < 2; j++) {
    int f = fgrp * 64 + (bn + j) * 16 + nl;
    float bias = b1[f];
    size_t sp = (size_t)(rowgrp * 64) + fgrp * 2 + ((bn + j) >> 1);
    int q2p = ((bn + j) & 1) * 2 + (nl >> 3);
#pragma unroll
    for (int i = 0; i < 2; i++) {
      int fiBase = (am + i) * 64 + q2p * 16 + (quad << 2);
#pragma unroll
      for (int r = 0; r < 4; r++) {
        float val = fmaxf(acc[i][j][r] + bias, 0.f);
        h1bf[(sp * 256 + fiBase + r) * 8 + jat] = f2b(val);
      }
    }
  }
}

// ---------------- FFN GEMM4 (MFMA, zero-LDS, ksp=8 + atomic): o2 += h1 @ w2^T ----------------
// wave = d-group (64 cols); A (h1bf) and B (w2bf) direct-global fragment order.
__global__ __launch_bounds__(256) void k_ffn2(const bf16* __restrict__ h1bf,
                                              const bf16* __restrict__ w2bf,
                                              float* __restrict__ o2) {
  int n = blockIdx.x;
  int rowgrp = n >> 3;             // 0..127
  int ksp = n & 7;                 // 0..7
  int tid = threadIdx.x;
  int wave = tid >> 6, lane = tid & 63;

  f32x4 acc[4][4];
#pragma unroll
  for (int i = 0; i < 4; i++)
#pragma unroll
    for (int j = 0; j < 4; j++) acc[i][j] = (f32x4){0.f, 0.f, 0.f, 0.f};

#pragma unroll
  for (int st = 0; st < 8; st++) {
    int sg = ksp * 8 + st;
    const bf16* Ab = h1bf + ((size_t)(rowgrp * 64 + sg) * 256) * 8;
    const bf16* Bbv = w2bf + ((size_t)(wave * 64 + sg) * 256) * 8;
    short8 af[4], bfr[4];
#pragma unroll
    for (int mt = 0; mt < 4; mt++)
      af[mt] = *(const short8*)(Ab + (size_t)(mt * 64 + lane) * 8);
#pragma unroll
    for (int nt = 0; nt < 4; nt++)
      bfr[nt] = *(const short8*)(Bbv + (size_t)(nt * 64 + lane) * 8);
#pragma unroll
    for (int mt = 0; mt < 4; mt++)
#pragma unroll
      for (int nt = 0; nt < 4; nt++) acc[mt][nt] = MFMA16(af[mt], bfr[nt], acc[mt][nt]);
  }
  int quad = lane >> 4, nl = lane & 15;
#pragma unroll
  for (int mt = 0; mt < 4; mt++)
#pragma unroll
    for (int r = 0; r < 4; r++) {
      int row = rowgrp * 64 + mt * 16 + quad * 4 + r;
#pragma unroll
      for (int nt = 0; nt < 4; nt++) {
        int col = wave * 64 + nt * 16 + nl;
        atomicAdd(&o2[(size_t)row * Dd + col], acc[mt][nt][r]);
      }
    }
}

// ---------------- LN_out: out = LN(o2 + b2 + t) with g3/be3 ----------------
__global__ __launch_bounds__(64) void k_ln_out(const float* __restrict__ o2,
                                               const float* __restrict__ b2v,
                                               const float* __restrict__ t,
                                               const float* __restrict__ g,
                                               const float* __restrict__ be,
                                               float* __restrict__ out) {
  int row = blockIdx.x;
  int lane = threadIdx.x;
  const float* po = o2 + (size_t)row * Dd + lane * 4;
  const float* pt = t + (size_t)row * Dd + lane * 4;
  float v[4];
#pragma unroll
  for (int u = 0; u < 4; u++) v[u] = po[u] + b2v[lane * 4 + u] + pt[u];
  float s1 = v[0] + v[1] + v[2] + v[3];
  float s2 = v[0] * v[0] + v[1] * v[1] + v[2] * v[2] + v[3] * v[3];
#pragma unroll
  for (int m = 32; m >= 1; m >>= 1) {
    s1 += __shfl_xor(s1, m, 64);
    s2 += __shfl_xor(s2, m, 64);
  }
  float mu = s1 * (1.0f / 256.0f);
  float var = s2 * (1.0f / 256.0f) - mu * mu;
  float rs = rsqrtf(fmaxf(var, 0.f) + LN_EPSf);
  float* pw = out + (size_t)row * Dd + lane * 4;
#pragma unroll
  for (int u = 0; u < 4; u++)
    pw[u] = (v[u] - mu) * rs * g[lane * 4 + u] + be[lane * 4 + u];
}

extern "C" void kernel_launch(void* const* d_in, const int* in_sizes, int n_in,
                              void* d_out, int out_size, void* d_ws, size_t ws_size,
                              hipStream_t stream) {
  const float* x = (const float*)d_in[0];
  const float* tgt = (const float*)d_in[1];
  const float* w1 = (const float*)d_in[2];
  const float* b1 = (const float*)d_in[3];
  const float* w2 = (const float*)d_in[4];
  const float* b2v = (const float*)d_in[5];
  const float* g2 = (const float*)d_in[6];
  const float* be2 = (const float*)d_in[7];
  const float* g3 = (const float*)d_in[8];
  const float* be3 = (const float*)d_in[9];
  float* out = (float*)d_out;

  // Aliasing (R8-proven): tbf->tnbf (dead after k_dots); o2->t2 (dead after ln_pre,
  // re-zeroed); w1bf/w2bf carved from attn_bf (dead after gemm2; prew after gemm2).
  char* w = (char*)d_ws;
  bf16* tnbf = (bf16*)w;     w += (size_t)Bb * Kk * Dd * 2;   // 4 MB
  float* S = (float*)w;      w += (size_t)Bb * Kk * 4;        // 32 KB
  float* t = (float*)w;      w += (size_t)Bb * Kk * Dd * 4;   // 8 MB
  float* t2 = (float*)w;     w += (size_t)Bb * Kk * Dd * 4;   // 8 MB
  bf16* attn_bf = (bf16*)w;  w += (size_t)Bb * HWw * Kk * 2;  // 64 MB
  bf16* h1bf = (bf16*)w;     w += (size_t)Bb * Kk * Ff * 2;   // 32 MB
  bf16* xb_bf = (bf16*)w;    w += (size_t)Bb * Dd * HWw * 2;  // 64 MB

  bf16* tbf = tnbf;                        // 4 MB alias
  float* o2 = t2;                          // 8 MB alias
  bf16* w1bf = attn_bf;                    // 1 MB carve
  bf16* w2bf = attn_bf + (size_t)Ff * Dd;  // 1 MB carve

  hipMemsetAsync(S, 0, (size_t)Bb * Kk * 4, stream);
  hipMemsetAsync(t2, 0, (size_t)Bb * Kk * Dd * 4, stream);
  k_tn<<<Bb * Kk, 64, 0, stream>>>(tgt, tnbf);
  k_dots<<<Bb * (HWw / 64), 256, 0, stream>>>(tnbf, x, xb_bf, attn_bf, S);
  k_gemm2<<<2048, 256, 0, stream>>>(attn_bf, xb_bf, t2);
  k_prew1<<<Ff, 64, 0, stream>>>(w1, w1bf);
  k_prew2<<<Dd, 64, 0, stream>>>(w2, w2bf);
  k_ln_pre<<<Bb * Kk, 64, 0, stream>>>(t2, S, tgt, g2, be2, t, tbf);
  hipMemsetAsync(o2, 0, (size_t)Bb * Kk * Dd * 4, stream);
  k_ffn1<<<(Bb * Kk / 64) * (Ff / 64), 256, 0, stream>>>(tbf, w1bf, b1, h1bf);
  k_ffn2<<<(Bb * Kk / 64) * 8, 256, 0, stream>>>(h1bf, w2bf, o2);
  k_ln_out<<<Bb * Kk, 64, 0, stream>>>(o2, b2v, t, g3, be3, out);
}